// Round 6
// baseline (328.659 us; speedup 1.0000x reference)
//
#include <hip/hip_runtime.h>
#include <math.h>

typedef __attribute__((ext_vector_type(8))) short bf16x8;
typedef __attribute__((ext_vector_type(4))) float f32x4;
typedef unsigned short u16;
typedef unsigned int u32;

#define DEVFN static __device__ __forceinline__

constexpr int NB  = 32;
constexpr int DLn = 290;
constexpr int PLc = 1000;
constexpr int MD  = NB * DLn;   // 9280  = 145*64
constexpr int MP  = NB * PLc;   // 32000 = 500*64

DEVFN u16 f2b(float f) {
    u32 u = __builtin_bit_cast(u32, f);
    u32 r = u + 0x7fffu + ((u >> 16) & 1u);
    return (u16)(r >> 16);
}
DEVFN float b2f(u16 s) { return __builtin_bit_cast(float, (u32)s << 16); }
DEVFN float sigm(float x) { return 1.0f / (1.0f + __expf(-x)); }
// XOR-swizzled LDS index (u16 units); stride multiple of 8 u16. 16B-aligned.
DEVFN int sw(int row, int col, int stride) { return row * stride + (col ^ ((row & 7) << 3)); }

// ---------------- PE table ----------------
__global__ void pe_kernel(float* __restrict__ pe) {
    int p = blockIdx.x, c = threadIdx.x;
    float div = __expf((float)(c & ~1) * (-9.210340371976184f / 256.0f));
    float ang = (float)p * div;
    pe[p * 256 + c] = (c & 1) ? cosf(ang) : sinf(ang);
}

// ---------------- weight prep: WT[n][k] bf16, LDS transpose ----------------
struct WPtrs { const float* w[10]; };
__global__ __launch_bounds__(256) void wprep_kernel(WPtrs wp, u16* __restrict__ wt) {
    __shared__ u16 t[64][66];
    int m = blockIdx.y, tile = blockIdx.x;
    int k0 = (tile >> 2) * 64, n0 = (tile & 3) * 64;
    const float* w = wp.w[m];
    int r = threadIdx.x >> 6, c = threadIdx.x & 63;
    #pragma unroll
    for (int q = 0; q < 16; q++) {
        int rr = r + q * 4;
        t[rr][c] = f2b(w[(size_t)(k0 + rr) * 256 + n0 + c]);
    }
    __syncthreads();
    #pragma unroll
    for (int q = 0; q < 16; q++) {
        int rr = r + q * 4;
        wt[((size_t)m << 16) + (size_t)(n0 + rr) * 256 + k0 + c] = t[c][rr];
    }
}

// ---------------- fused projection: C[mi] = act(A @ BT[mi]^T + bias[mi]) ----------------
// One block per 64-row A strip. A fragments resident in registers (loaded once,
// optionally built on-the-fly as bf16(x + scale*pe) from fp32 input). B streamed
// through double-buffered swizzled LDS in 64-n-row chunks, full K=256 per phase.
struct PM { const u16* BT; const float* bias; u16* C; int sig; };
struct PCfg {
    const u16* Ab;       // bf16 A (or null)
    const float* Af32;   // fp32 X (or null) -> e = x + scale*pe
    const float* scale;
    const float* pe;
    int plen;            // PE period (290 / 1000)
    int mrows;
    int nmat;
    PM m[4];
};
struct PCfg2 { PCfg c[2]; int split; };

__global__ __launch_bounds__(256) void proj_kernel(PCfg2 cfgs) {
    const int bid = blockIdx.x;
    const PCfg cfg = (bid < cfgs.split) ? cfgs.c[0] : cfgs.c[1];
    const int mt = (bid < cfgs.split) ? bid : bid - cfgs.split;
    __shared__ u16 Bs[2][64 * 256];
    const int tid = threadIdx.x;
    const int lane = tid & 63, w = tid >> 6, ln = lane & 15, g = lane >> 4;
    const int m0 = w * 16;

    // ---- A fragments in registers: rows mt*64 + m0 + ln, cols ks*32+g*8 ----
    bf16x8 Af[8];
    {
        const int row = mt * 64 + m0 + ln;
        if (cfg.Af32) {
            const int i = row % cfg.plen;
            const float s = cfg.scale[0];
            const float* Xp_ = cfg.Af32 + (size_t)row * 256 + g * 8;
            const float* Pe_ = cfg.pe + (size_t)i * 256 + g * 8;
            #pragma unroll
            for (int ks = 0; ks < 8; ks++) {
                float4 xa = *(const float4*)(Xp_ + ks * 32);
                float4 xb = *(const float4*)(Xp_ + ks * 32 + 4);
                float4 pa = *(const float4*)(Pe_ + ks * 32);
                float4 pb = *(const float4*)(Pe_ + ks * 32 + 4);
                u16 o[8];
                o[0] = f2b(xa.x + s * pa.x); o[1] = f2b(xa.y + s * pa.y);
                o[2] = f2b(xa.z + s * pa.z); o[3] = f2b(xa.w + s * pa.w);
                o[4] = f2b(xb.x + s * pb.x); o[5] = f2b(xb.y + s * pb.y);
                o[6] = f2b(xb.z + s * pb.z); o[7] = f2b(xb.w + s * pb.w);
                Af[ks] = *(bf16x8*)o;
            }
        } else {
            const u16* Ap = cfg.Ab + (size_t)row * 256 + g * 8;
            #pragma unroll
            for (int ks = 0; ks < 8; ks++)
                Af[ks] = *(const bf16x8*)(Ap + ks * 32);
        }
    }

    // staging: thread writes 8 x 16B of B chunk; rows lr, col base lc*8
    const int lr = tid >> 2, lc = tid & 3;
    const int nphase = cfg.nmat * 4;

    // prologue: stage phase 0 (matrix 0, chunk 0)
    {
        const u16* Bp = cfg.m[0].BT + (size_t)lr * 256 + lc * 8;
        uint4 bv[8];
        #pragma unroll
        for (int kk = 0; kk < 8; kk++) bv[kk] = *(const uint4*)(Bp + kk * 32);
        #pragma unroll
        for (int kk = 0; kk < 8; kk++) *(uint4*)&Bs[0][sw(lr, lc * 8 + kk * 32, 256)] = bv[kk];
    }
    __syncthreads();

    for (int ph = 0; ph < nphase; ph++) {
        const int cur = ph & 1;
        // prefetch next chunk to regs
        uint4 bv[8];
        if (ph + 1 < nphase) {
            const int mi = (ph + 1) >> 2, c = (ph + 1) & 3;
            const u16* Bp = cfg.m[mi].BT + (size_t)(c * 64 + lr) * 256 + lc * 8;
            #pragma unroll
            for (int kk = 0; kk < 8; kk++) bv[kk] = *(const uint4*)(Bp + kk * 32);
        }
        // compute 64x64 output chunk, full K
        f32x4 acc[4] = {};
        #pragma unroll
        for (int ks = 0; ks < 8; ks++) {
            #pragma unroll
            for (int nt = 0; nt < 4; nt++) {
                bf16x8 bf = *(const bf16x8*)&Bs[cur][sw(nt * 16 + ln, ks * 32 + g * 8, 256)];
                acc[nt] = __builtin_amdgcn_mfma_f32_16x16x32_bf16(Af[ks], bf, acc[nt], 0, 0, 0);
            }
        }
        // epilogue: bias + optional sigmoid, write
        {
            const int mi = ph >> 2, c = ph & 3;
            const PM pm = cfg.m[mi];
            const int rowb = mt * 64 + m0 + g * 4;
            #pragma unroll
            for (int nt = 0; nt < 4; nt++) {
                const int n = c * 64 + nt * 16 + ln;
                const float bb = pm.bias[n];
                #pragma unroll
                for (int r = 0; r < 4; r++) {
                    float v = acc[nt][r] + bb;
                    if (pm.sig) v = sigm(v);
                    pm.C[(size_t)(rowb + r) * 256 + n] = f2b(v);
                }
            }
        }
        __syncthreads();
        if (ph + 1 < nphase) {
            #pragma unroll
            for (int kk = 0; kk < 8; kk++) *(uint4*)&Bs[cur ^ 1][sw(lr, lc * 8 + kk * 32, 256)] = bv[kk];
        }
        __syncthreads();
    }
}

// ---------------- attention: one block per (b,h), no-max softmax, 2 sweeps ----------------
__global__ __launch_bounds__(512) void attn_kernel(
        const u16* __restrict__ Qd, const u16* __restrict__ Kd, const u16* __restrict__ Vd,
        const u16* __restrict__ Kp, const u16* __restrict__ Vp, const u16* __restrict__ Qp,
        const float* __restrict__ alpha,
        u16* __restrict__ ctx_d, u16* __restrict__ ctx_p, float* __restrict__ cm) {
    __shared__ u16 Ks[2][64 * 64];
    __shared__ union {
        struct { u16 VpT[2][32 * 64]; u16 Pm[320 * 64]; } s1;
        struct { u16 PT[64 * 320]; u16 VdT[32 * 320]; } s2;
    } U;
    __shared__ float r_l[320];
    __shared__ float colpart[8][64];

    const int bh = blockIdx.x, b = bh >> 3, h = bh & 7;
    const int tid = threadIdx.x;
    const int w = tid >> 6, lane = tid & 63, ln = lane & 15, g = lane >> 4;

    const float a = sigm(alpha[0]);
    const float inv = 0.1767766952966369f;
    const float sa = a * inv, sb = (1.0f - a) * inv;
    const int nmt = (w < 4) ? 3 : 2;
    const int mtsA[3] = { w, w + 8, w + 16 };

    const size_t rbd = (size_t)b * DLn * 256 + h * 32;
    const size_t rbp = (size_t)b * PLc * 256 + h * 32;

    bf16x8 Qf[3][2];
    #pragma unroll
    for (int t = 0; t < 3; t++) {
        const int i = mtsA[t] * 16 + ln;
        #pragma unroll
        for (int ks = 0; ks < 2; ks++) {
            u16 o[8] = {0,0,0,0,0,0,0,0};
            if (t < nmt && i < DLn) {
                const u16* src = (ks ? Kd : Qd) + rbd + (size_t)i * 256 + g * 8;
                const float s = ks ? sb : sa;
                uint4 v = *(const uint4*)src;
                u16 e[8]; *(uint4*)e = v;
                #pragma unroll
                for (int q = 0; q < 8; q++) o[q] = f2b(b2f(e[q]) * s);
            }
            Qf[t][ks] = *(bf16x8*)o;
        }
    }

    const int s_jj = tid >> 3, s_ch = tid & 7;
    const u16* s_src = ((s_ch >> 2) ? Qp : Kp) + rbp + (s_ch & 3) * 8;
    const int v_j = tid & 63, v_d0 = (tid >> 6) * 4;

    {
        int j = s_jj;
        uint4 kv = (j < PLc) ? *(const uint4*)(s_src + (size_t)j * 256) : make_uint4(0,0,0,0);
        uint2 vv = (v_j < PLc) ? *(const uint2*)(Vp + rbp + (size_t)v_j * 256 + v_d0) : make_uint2(0,0);
        *(uint4*)&Ks[0][sw(s_jj, s_ch * 8, 64)] = kv;
        u16 e[4]; *(uint2*)e = vv;
        #pragma unroll
        for (int q = 0; q < 4; q++) U.s1.VpT[0][sw(v_d0 + q, v_j, 64)] = e[q];
    }
    __syncthreads();

    float rs[3] = {0.f, 0.f, 0.f};
    f32x4 accd[3][2] = {};
    for (int jt = 0; jt < 16; jt++) {
        const int cur = jt & 1, j0 = jt * 64;
        const int jn = j0 + 64 + s_jj;
        uint4 kv = (jn < PLc) ? *(const uint4*)(s_src + (size_t)jn * 256) : make_uint4(0,0,0,0);
        const int vn = j0 + 64 + v_j;
        uint2 vv = (vn < PLc) ? *(const uint2*)(Vp + rbp + (size_t)vn * 256 + v_d0) : make_uint2(0,0);

        bf16x8 kf[4][2];
        #pragma unroll
        for (int js = 0; js < 4; js++)
            #pragma unroll
            for (int ks = 0; ks < 2; ks++)
                kf[js][ks] = *(const bf16x8*)&Ks[cur][sw(js * 16 + ln, ks * 32 + g * 8, 64)];

        #pragma unroll
        for (int t = 0; t < 3; t++) {
            if (t >= nmt) break;
            const int mt = mtsA[t];
            f32x4 acc[4] = {};
            #pragma unroll
            for (int ks = 0; ks < 2; ks++)
                #pragma unroll
                for (int js = 0; js < 4; js++)
                    acc[js] = __builtin_amdgcn_mfma_f32_16x16x32_bf16(kf[js][ks], Qf[t][ks], acc[js], 0, 0, 0);
            const int irow = mt * 16 + ln;
            #pragma unroll
            for (int js = 0; js < 4; js++) {
                u16 pb[4];
                float psum = 0.f;
                #pragma unroll
                for (int r = 0; r < 4; r++) {
                    float p = __expf(acc[js][r]);
                    psum += p;
                    pb[r] = f2b(p);
                }
                rs[t] += psum;
                *(ushort4*)&U.s1.Pm[sw(irow, js * 16 + g * 4, 64)] = *(ushort4*)pb;
            }
        }
        #pragma unroll
        for (int t = 0; t < 3; t++) {
            if (t >= nmt) break;
            const int mt = mtsA[t];
            #pragma unroll
            for (int ks2 = 0; ks2 < 2; ks2++) {
                bf16x8 af = *(const bf16x8*)&U.s1.Pm[sw(mt * 16 + ln, ks2 * 32 + g * 8, 64)];
                #pragma unroll
                for (int nd = 0; nd < 2; nd++) {
                    bf16x8 bv = *(const bf16x8*)&U.s1.VpT[cur][sw(nd * 16 + ln, ks2 * 32 + g * 8, 64)];
                    accd[t][nd] = __builtin_amdgcn_mfma_f32_16x16x32_bf16(af, bv, accd[t][nd], 0, 0, 0);
                }
            }
        }
        *(uint4*)&Ks[cur ^ 1][sw(s_jj, s_ch * 8, 64)] = kv;
        {
            u16 e[4]; *(uint2*)e = vv;
            #pragma unroll
            for (int q = 0; q < 4; q++) U.s1.VpT[cur ^ 1][sw(v_d0 + q, v_j, 64)] = e[q];
        }
        __syncthreads();
    }

    #pragma unroll
    for (int t = 0; t < 3; t++) {
        float v = rs[t];
        v += __shfl_xor(v, 16);
        v += __shfl_xor(v, 32);
        rs[t] = v;
    }
    if (g == 0) {
        #pragma unroll
        for (int t = 0; t < 3; t++) {
            if (t >= nmt) break;
            const int i = mtsA[t] * 16 + ln;
            r_l[i] = (i < DLn) ? 1.0f / (rs[t] - 24.0f) : 0.0f;
        }
    }
    __syncthreads();

    #pragma unroll
    for (int t = 0; t < 3; t++) {
        if (t >= nmt) break;
        const int mt = mtsA[t];
        #pragma unroll
        for (int r = 0; r < 4; r++) {
            const int i = mt * 16 + g * 4 + r;
            if (i < DLn) {
                const float ri = r_l[i];
                #pragma unroll
                for (int nd = 0; nd < 2; nd++)
                    ctx_d[rbd + (size_t)i * 256 + nd * 16 + ln] = f2b(accd[t][nd][r] * ri);
            }
        }
    }
    for (int c = tid; c < 320 * 8; c += 512) {
        const int i = c >> 3, d0 = (c & 7) * 4;
        u16 o[4] = {0,0,0,0};
        if (i < DLn) {
            const float ri = r_l[i];
            uint2 v = *(const uint2*)(Vd + rbd + (size_t)i * 256 + d0);
            u16 e[4]; *(uint2*)e = v;
            #pragma unroll
            for (int q = 0; q < 4; q++) o[q] = f2b(b2f(e[q]) * ri);
        }
        #pragma unroll
        for (int q = 0; q < 4; q++) U.s2.VdT[sw(d0 + q, i, 320)] = o[q];
    }
    {
        int j = s_jj;
        uint4 kv = (j < PLc) ? *(const uint4*)(s_src + (size_t)j * 256) : make_uint4(0,0,0,0);
        *(uint4*)&Ks[0][sw(s_jj, s_ch * 8, 64)] = kv;
    }
    float rr[3][4];
    #pragma unroll
    for (int t = 0; t < 3; t++)
        #pragma unroll
        for (int r = 0; r < 4; r++)
            rr[t][r] = (t < nmt) ? r_l[mtsA[t] * 16 + g * 4 + r] : 0.0f;
    __syncthreads();

    for (int jt = 0; jt < 16; jt++) {
        const int cur = jt & 1, j0 = jt * 64;
        const int jn = j0 + 64 + s_jj;
        uint4 kv = (jn < PLc) ? *(const uint4*)(s_src + (size_t)jn * 256) : make_uint4(0,0,0,0);

        bf16x8 kf[4][2];
        #pragma unroll
        for (int js = 0; js < 4; js++)
            #pragma unroll
            for (int ks = 0; ks < 2; ks++)
                kf[js][ks] = *(const bf16x8*)&Ks[cur][sw(js * 16 + ln, ks * 32 + g * 8, 64)];

        float csl[4] = {0.f, 0.f, 0.f, 0.f};
        #pragma unroll
        for (int t = 0; t < 3; t++) {
            if (t >= nmt) break;
            const int mt = mtsA[t];
            f32x4 acc[4] = {};
            #pragma unroll
            for (int ks = 0; ks < 2; ks++)
                #pragma unroll
                for (int js = 0; js < 4; js++)
                    acc[js] = __builtin_amdgcn_mfma_f32_16x16x32_bf16(Qf[t][ks], kf[js][ks], acc[js], 0, 0, 0);
            #pragma unroll
            for (int js = 0; js < 4; js++) {
                u16 pb[4];
                #pragma unroll
                for (int r = 0; r < 4; r++) {
                    float p = __expf(acc[js][r]);
                    csl[js] += p * rr[t][r];
                    pb[r] = f2b(p);
                }
                *(ushort4*)&U.s2.PT[sw(js * 16 + ln, mt * 16 + g * 4, 320)] = *(ushort4*)pb;
            }
        }
        #pragma unroll
        for (int js = 0; js < 4; js++) {
            float v = csl[js];
            v += __shfl_xor(v, 16);
            v += __shfl_xor(v, 32);
            csl[js] = v;
        }
        if (g == 0) {
            #pragma unroll
            for (int js = 0; js < 4; js++) colpart[w][js * 16 + ln] = csl[js];
        }
        *(uint4*)&Ks[cur ^ 1][sw(s_jj, s_ch * 8, 64)] = kv;
        __syncthreads();

        {
            const int js2 = w & 3, ds2 = w >> 2;
            f32x4 ap = {};
            #pragma unroll
            for (int k = 0; k < 10; k++) {
                bf16x8 af = *(const bf16x8*)&U.s2.PT[sw(js2 * 16 + ln, k * 32 + g * 8, 320)];
                bf16x8 bv = *(const bf16x8*)&U.s2.VdT[sw(ds2 * 16 + ln, k * 32 + g * 8, 320)];
                ap = __builtin_amdgcn_mfma_f32_16x16x32_bf16(af, bv, ap, 0, 0, 0);
            }
            const int d = ds2 * 16 + ln;
            #pragma unroll
            for (int r = 0; r < 4; r++) {
                const int j = j0 + js2 * 16 + g * 4 + r;
                if (j < PLc) ctx_p[rbp + (size_t)j * 256 + d] = f2b(ap[r]);
            }
        }
        if (w == 0) {
            float tot = 0.f;
            #pragma unroll
            for (int ww = 0; ww < 8; ww++) tot += colpart[ww][lane];
            const int j = j0 + lane;
            if (j < PLc) cm[(size_t)(b * PLc + j) * 8 + h] = tot * (1.0f / 290.0f);
        }
        __syncthreads();
    }
}

// ---------------- final combine, 4 cols/thread ----------------
__global__ __launch_bounds__(256) void combine_kernel(
        const float* __restrict__ drug, const float* __restrict__ prot,
        const float* __restrict__ scale_d, const float* __restrict__ scale_p,
        const float* __restrict__ pe,
        const u16* __restrict__ Xd, const u16* __restrict__ Xp,
        const u16* __restrict__ gate_d, const u16* __restrict__ gate_p,
        const float* __restrict__ cm,
        const float* __restrict__ w_fc_dp, const float* __restrict__ b_fc_dp,
        const float* __restrict__ w_fc_pd, const float* __restrict__ b_fc_pd,
        float* __restrict__ out) {
    int idx = blockIdx.x * 256 + threadIdx.x;
    int r = idx >> 6, c4 = (idx & 63) * 4;
    if (r < MD) {
        int b = r / DLn, i = r % DLn;
        float s = scale_d[0];
        float4 dv = *(const float4*)&drug[(size_t)r * 256 + c4];
        float4 pv = *(const float4*)&pe[i * 256 + c4];
        uint2 xv = *(const uint2*)&Xd[(size_t)r * 256 + c4];
        uint2 gv = *(const uint2*)&gate_d[(size_t)r * 256 + c4];
        float4 bb = *(const float4*)&b_fc_dp[c4];
        float da[4] = { bb.x, bb.y, bb.z, bb.w };
        #pragma unroll
        for (int hh = 0; hh < 8; hh++) {
            float4 wv = *(const float4*)&w_fc_dp[hh * 256 + c4];
            da[0] += 0.001f * wv.x; da[1] += 0.001f * wv.y;
            da[2] += 0.001f * wv.z; da[3] += 0.001f * wv.w;
        }
        u16 xe[4]; *(uint2*)xe = xv;
        u16 ge[4]; *(uint2*)ge = gv;
        float e0 = dv.x + s * pv.x, e1 = dv.y + s * pv.y;
        float e2 = dv.z + s * pv.z, e3 = dv.w + s * pv.w;
        float4 o;
        o.x = e0 + b2f(xe[0]) * b2f(ge[0]) * sigm(da[0]);
        o.y = e1 + b2f(xe[1]) * b2f(ge[1]) * sigm(da[1]);
        o.z = e2 + b2f(xe[2]) * b2f(ge[2]) * sigm(da[2]);
        o.w = e3 + b2f(xe[3]) * b2f(ge[3]) * sigm(da[3]);
        *(float4*)&out[((size_t)b * 1290 + i) * 256 + c4] = o;
    } else {
        int rr = r - MD;
        int b = rr / PLc, j = rr % PLc;
        float s = scale_p[0];
        float4 dv = *(const float4*)&prot[(size_t)rr * 256 + c4];
        float4 pv = *(const float4*)&pe[j * 256 + c4];
        uint2 xv = *(const uint2*)&Xp[(size_t)rr * 256 + c4];
        uint2 gv = *(const uint2*)&gate_p[(size_t)rr * 256 + c4];
        float4 bb = *(const float4*)&b_fc_pd[c4];
        float pa[4] = { bb.x, bb.y, bb.z, bb.w };
        #pragma unroll
        for (int hh = 0; hh < 8; hh++) {
            float cmh = cm[(size_t)rr * 8 + hh];
            float4 wv = *(const float4*)&w_fc_pd[hh * 256 + c4];
            pa[0] += cmh * wv.x; pa[1] += cmh * wv.y;
            pa[2] += cmh * wv.z; pa[3] += cmh * wv.w;
        }
        u16 xe[4]; *(uint2*)xe = xv;
        u16 ge[4]; *(uint2*)ge = gv;
        float e0 = dv.x + s * pv.x, e1 = dv.y + s * pv.y;
        float e2 = dv.z + s * pv.z, e3 = dv.w + s * pv.w;
        float4 o;
        o.x = e0 + b2f(xe[0]) * b2f(ge[0]) * sigm(pa[0]);
        o.y = e1 + b2f(xe[1]) * b2f(ge[1]) * sigm(pa[1]);
        o.z = e2 + b2f(xe[2]) * b2f(ge[2]) * sigm(pa[2]);
        o.w = e3 + b2f(xe[3]) * b2f(ge[3]) * sigm(pa[3]);
        *(float4*)&out[((size_t)b * 1290 + 290 + j) * 256 + c4] = o;
    }
}

extern "C" void kernel_launch(void* const* d_in, const int* in_sizes, int n_in,
                              void* d_out, int out_size, void* d_ws, size_t ws_size,
                              hipStream_t stream) {
    (void)in_sizes; (void)n_in; (void)out_size;
    const float* drug    = (const float*)d_in[0];
    const float* prot    = (const float*)d_in[1];
    const float* scale_d = (const float*)d_in[2];
    const float* scale_p = (const float*)d_in[3];

    char* ws = (char*)d_ws;
    size_t off = 0;
    auto alloc = [&](size_t bytes) -> void* {
        void* p = ws + off;
        off += (bytes + 255) & ~(size_t)255;
        return p;
    };
    float* pe   = (float*)alloc((size_t)1000 * 256 * 4);
    u16* wt     = (u16*)alloc((size_t)10 * 65536 * 2);
    u16* Qd     = (u16*)alloc((size_t)MD * 256 * 2);
    u16* Kd     = (u16*)alloc((size_t)MD * 256 * 2);
    u16* Vd     = (u16*)alloc((size_t)MD * 256 * 2);
    u16* gate_d = (u16*)alloc((size_t)MD * 256 * 2);
    u16* Kp     = (u16*)alloc((size_t)MP * 256 * 2);
    u16* Vp     = (u16*)alloc((size_t)MP * 256 * 2);
    u16* Qp     = (u16*)alloc((size_t)MP * 256 * 2);
    u16* gate_p = (u16*)alloc((size_t)MP * 256 * 2);
    u16* ctxd   = (u16*)alloc((size_t)MD * 256 * 2);
    u16* ctxp   = (u16*)alloc((size_t)MP * 256 * 2);
    float* cm   = (float*)alloc((size_t)MP * 8 * 4);
    u16* Xd     = (u16*)alloc((size_t)MD * 256 * 2);
    u16* Xp     = (u16*)alloc((size_t)MP * 256 * 2);
    if (off > ws_size) return;

    pe_kernel<<<1000, 256, 0, stream>>>(pe);

    WPtrs wp;
    const int wsrc[10] = {4, 12, 14, 25, 6, 8, 10, 27, 16, 18};
    for (int m = 0; m < 10; m++) wp.w[m] = (const float*)d_in[wsrc[m]];
    wprep_kernel<<<dim3(16, 10), 256, 0, stream>>>(wp, wt);

    auto W = [&](int slot) { return wt + (size_t)slot * 65536; };

    // proj1: e = x + scale*pe computed on the fly; 4 outputs per strip
    PCfg2 p1;
    p1.split = 145;
    p1.c[0] = { nullptr, drug, scale_d, pe, DLn, MD, 4,
                { { W(0), (const float*)d_in[5],  Qd,     0 },
                  { W(1), (const float*)d_in[13], Kd,     0 },
                  { W(2), (const float*)d_in[15], Vd,     0 },
                  { W(3), (const float*)d_in[26], gate_d, 1 } } };
    p1.c[1] = { nullptr, prot, scale_p, pe, PLc, MP, 4,
                { { W(4), (const float*)d_in[7],  Kp,     0 },
                  { W(5), (const float*)d_in[9],  Vp,     0 },
                  { W(6), (const float*)d_in[11], Qp,     0 },
                  { W(7), (const float*)d_in[28], gate_p, 1 } } };
    proj_kernel<<<645, 256, 0, stream>>>(p1);

    attn_kernel<<<256, 512, 0, stream>>>(Qd, Kd, Vd, Kp, Vp, Qp,
                                         (const float*)d_in[20], ctxd, ctxp, cm);

    // proj2: output projections
    PCfg2 p2;
    p2.split = 145;
    p2.c[0] = { ctxd, nullptr, nullptr, nullptr, DLn, MD, 1,
                { { W(8), (const float*)d_in[17], Xd, 0 }, {}, {}, {} } };
    p2.c[1] = { ctxp, nullptr, nullptr, nullptr, PLc, MP, 1,
                { { W(9), (const float*)d_in[19], Xp, 0 }, {}, {}, {} } };
    proj_kernel<<<645, 256, 0, stream>>>(p2);

    combine_kernel<<<(MD + MP) / 4, 256, 0, stream>>>(drug, prot, scale_d, scale_p, pe,
        Xd, Xp, gate_d, gate_p, cm,
        (const float*)d_in[21], (const float*)d_in[22],
        (const float*)d_in[23], (const float*)d_in[24],
        (float*)d_out);
}

// Round 7
// 265.352 us; speedup vs baseline: 1.2386x; 1.2386x over previous
//
#include <hip/hip_runtime.h>
#include <math.h>

typedef __attribute__((ext_vector_type(8))) short bf16x8;
typedef __attribute__((ext_vector_type(4))) float f32x4;
typedef unsigned short u16;
typedef unsigned int u32;

#define DEVFN static __device__ __forceinline__

constexpr int NB  = 32;
constexpr int DLn = 290;
constexpr int PLc = 1000;
constexpr int MD  = NB * DLn;   // 9280  = 145*64
constexpr int MP  = NB * PLc;   // 32000 = 500*64

DEVFN u16 f2b(float f) {
    u32 u = __builtin_bit_cast(u32, f);
    u32 r = u + 0x7fffu + ((u >> 16) & 1u);
    return (u16)(r >> 16);
}
DEVFN float b2f(u16 s) { return __builtin_bit_cast(float, (u32)s << 16); }
DEVFN float sigm(float x) { return 1.0f / (1.0f + __expf(-x)); }
// XOR-swizzled LDS index (u16 units); stride multiple of 8 u16. 16B-aligned.
DEVFN int sw(int row, int col, int stride) { return row * stride + (col ^ ((row & 7) << 3)); }

// ---------------- PE table ----------------
__global__ void pe_kernel(float* __restrict__ pe) {
    int p = blockIdx.x, c = threadIdx.x;
    float div = __expf((float)(c & ~1) * (-9.210340371976184f / 256.0f));
    float ang = (float)p * div;
    pe[p * 256 + c] = (c & 1) ? cosf(ang) : sinf(ang);
}

// ---------------- weight prep: WT[n][k] bf16, LDS transpose ----------------
struct WPtrs { const float* w[10]; };
__global__ __launch_bounds__(256) void wprep_kernel(WPtrs wp, u16* __restrict__ wt) {
    __shared__ u16 t[64][66];
    int m = blockIdx.y, tile = blockIdx.x;
    int k0 = (tile >> 2) * 64, n0 = (tile & 3) * 64;
    const float* w = wp.w[m];
    int r = threadIdx.x >> 6, c = threadIdx.x & 63;
    #pragma unroll
    for (int q = 0; q < 16; q++) {
        int rr = r + q * 4;
        t[rr][c] = f2b(w[(size_t)(k0 + rr) * 256 + n0 + c]);
    }
    __syncthreads();
    #pragma unroll
    for (int q = 0; q < 16; q++) {
        int rr = r + q * 4;
        wt[((size_t)m << 16) + (size_t)(n0 + rr) * 256 + k0 + c] = t[c][rr];
    }
}

// ---------------- fused projection ----------------
// One block per 64-row A strip; A fragments in registers (once). B streamed via
// double-buffered swizzled LDS, 64-n chunks permuted by nu() so the swapped-operand
// MFMA (D = B-frag * A-frag = C^T fragment) leaves each thread with ONE C-row and
// 16 CONSECUTIVE cols -> 2x uint4 stores, full 64B sectors per store instruction.
struct PM { const u16* BT; const float* bias; u16* C; int sig; };
struct PCfg {
    const u16* Ab;       // bf16 A (or null)
    const float* Af32;   // fp32 X (or null) -> e = x + scale*pe
    const float* scale;
    const float* pe;
    int plen;
    PM m[4];
};
struct PCfg2 { PCfg c0, c1; int split; };

template<int NMAT>
__global__ __launch_bounds__(256) void proj_kernel(PCfg2 cfgs) {
    const int bid = blockIdx.x;
    const bool first = bid < cfgs.split;
    const PCfg* __restrict__ cfg = first ? &cfgs.c0 : &cfgs.c1;
    const int mt = first ? bid : bid - cfgs.split;
    __shared__ u16 Bs[2][64 * 256];
    const int tid = threadIdx.x;
    const int lane = tid & 63, w = tid >> 6, ln = lane & 15, g = lane >> 4;

    // ---- A fragments in registers: row mt*64 + w*16 + ln, k = ks*32 + g*8 ----
    bf16x8 Af[8];
    {
        const int row = mt * 64 + w * 16 + ln;
        if (cfg->Af32) {
            const int i = row % cfg->plen;
            const float s = cfg->scale[0];
            const float* Xp_ = cfg->Af32 + (size_t)row * 256 + g * 8;
            const float* Pe_ = cfg->pe + (size_t)i * 256 + g * 8;
            #pragma unroll
            for (int ks = 0; ks < 8; ks++) {
                float4 xa = *(const float4*)(Xp_ + ks * 32);
                float4 xb = *(const float4*)(Xp_ + ks * 32 + 4);
                float4 pa = *(const float4*)(Pe_ + ks * 32);
                float4 pb = *(const float4*)(Pe_ + ks * 32 + 4);
                u16 o[8];
                o[0] = f2b(xa.x + s * pa.x); o[1] = f2b(xa.y + s * pa.y);
                o[2] = f2b(xa.z + s * pa.z); o[3] = f2b(xa.w + s * pa.w);
                o[4] = f2b(xb.x + s * pb.x); o[5] = f2b(xb.y + s * pb.y);
                o[6] = f2b(xb.z + s * pb.z); o[7] = f2b(xb.w + s * pb.w);
                Af[ks] = *(bf16x8*)o;
            }
        } else {
            const u16* Ap = cfg->Ab + (size_t)row * 256 + g * 8;
            #pragma unroll
            for (int ks = 0; ks < 8; ks++)
                Af[ks] = *(const bf16x8*)(Ap + ks * 32);
        }
    }

    // staging: slot lr holds BT row (chunk*64 + nu(lr)); bit-permutation nu makes
    // the swapped-MFMA output columns consecutive per thread.
    const int lr = tid >> 2, lc = tid & 3;
    const int nu = ((lr >> 5) & 1) * 32 + ((lr >> 2) & 3) * 8 + ((lr >> 4) & 1) * 4 + (lr & 3);

    // prologue: stage (matrix 0, chunk 0)
    {
        const u16* Bp = cfg->m[0].BT + (size_t)nu * 256 + lc * 8;
        uint4 bv[8];
        #pragma unroll
        for (int kk = 0; kk < 8; kk++) bv[kk] = *(const uint4*)(Bp + kk * 32);
        #pragma unroll
        for (int kk = 0; kk < 8; kk++) *(uint4*)&Bs[0][sw(lr, lc * 8 + kk * 32, 256)] = bv[kk];
    }
    __syncthreads();

    #pragma unroll
    for (int mi = 0; mi < NMAT; mi++) {
        #pragma unroll
        for (int c = 0; c < 4; c++) {
            const int ph = mi * 4 + c, cur = ph & 1;
            uint4 bv[8];
            constexpr int NPH = NMAT * 4;
            const bool hasNext = (ph + 1 < NPH);
            if (hasNext) {
                const int nmi = (ph + 1) >> 2, nc = (ph + 1) & 3;
                const u16* Bp = cfg->m[nmi].BT + (size_t)(nc * 64 + nu) * 256 + lc * 8;
                #pragma unroll
                for (int kk = 0; kk < 8; kk++) bv[kk] = *(const uint4*)(Bp + kk * 32);
            }
            // compute: D = Bfrag * Afrag  (C^T fragment)
            f32x4 acc[4] = {};
            #pragma unroll
            for (int ks = 0; ks < 8; ks++) {
                #pragma unroll
                for (int nt = 0; nt < 4; nt++) {
                    bf16x8 bf = *(const bf16x8*)&Bs[cur][sw(nt * 16 + ln, ks * 32 + g * 8, 256)];
                    acc[nt] = __builtin_amdgcn_mfma_f32_16x16x32_bf16(bf, Af[ks], acc[nt], 0, 0, 0);
                }
            }
            // epilogue: thread owns row mt*64+w*16+ln, cols base0..base0+7 and base1..base1+7
            {
                const PM pm = cfg->m[mi];
                const int row = mt * 64 + w * 16 + ln;
                const int base0 = c * 64 + g * 8, base1 = base0 + 32;
                f32x4 b0 = *(const f32x4*)&pm.bias[base0];
                f32x4 b1 = *(const f32x4*)&pm.bias[base0 + 4];
                f32x4 b2 = *(const f32x4*)&pm.bias[base1];
                f32x4 b3 = *(const f32x4*)&pm.bias[base1 + 4];
                float v[16];
                #pragma unroll
                for (int t = 0; t < 4; t++) {
                    v[t]      = acc[0][t] + b0[t];
                    v[4 + t]  = acc[1][t] + b1[t];
                    v[8 + t]  = acc[2][t] + b2[t];
                    v[12 + t] = acc[3][t] + b3[t];
                }
                if (pm.sig) {
                    #pragma unroll
                    for (int t = 0; t < 16; t++) v[t] = sigm(v[t]);
                }
                u16 o[16];
                #pragma unroll
                for (int t = 0; t < 16; t++) o[t] = f2b(v[t]);
                u16* Cp = pm.C + (size_t)row * 256;
                *(uint4*)&Cp[base0] = *(uint4*)&o[0];
                *(uint4*)&Cp[base1] = *(uint4*)&o[8];
            }
            __syncthreads();
            if (hasNext) {
                #pragma unroll
                for (int kk = 0; kk < 8; kk++) *(uint4*)&Bs[cur ^ 1][sw(lr, lc * 8 + kk * 32, 256)] = bv[kk];
            }
            __syncthreads();
        }
    }
}

// ---------------- attention: one block per (b,h), no-max softmax, 2 sweeps ----------------
__global__ __launch_bounds__(512) void attn_kernel(
        const u16* __restrict__ Qd, const u16* __restrict__ Kd, const u16* __restrict__ Vd,
        const u16* __restrict__ Kp, const u16* __restrict__ Vp, const u16* __restrict__ Qp,
        const float* __restrict__ alpha,
        u16* __restrict__ ctx_d, u16* __restrict__ ctx_p, float* __restrict__ cm) {
    __shared__ u16 Ks[2][64 * 64];
    __shared__ union {
        struct { u16 VpT[2][32 * 64]; u16 Pm[320 * 64]; } s1;
        struct { u16 PT[64 * 320]; u16 VdT[32 * 320]; } s2;
    } U;
    __shared__ float r_l[320];
    __shared__ float colpart[8][64];

    const int bh = blockIdx.x, b = bh >> 3, h = bh & 7;
    const int tid = threadIdx.x;
    const int w = tid >> 6, lane = tid & 63, ln = lane & 15, g = lane >> 4;

    const float a = sigm(alpha[0]);
    const float inv = 0.1767766952966369f;
    const float sa = a * inv, sb = (1.0f - a) * inv;
    const int nmt = (w < 4) ? 3 : 2;
    const int mtsA[3] = { w, w + 8, w + 16 };

    const size_t rbd = (size_t)b * DLn * 256 + h * 32;
    const size_t rbp = (size_t)b * PLc * 256 + h * 32;

    bf16x8 Qf[3][2];
    #pragma unroll
    for (int t = 0; t < 3; t++) {
        const int i = mtsA[t] * 16 + ln;
        #pragma unroll
        for (int ks = 0; ks < 2; ks++) {
            u16 o[8] = {0,0,0,0,0,0,0,0};
            if (t < nmt && i < DLn) {
                const u16* src = (ks ? Kd : Qd) + rbd + (size_t)i * 256 + g * 8;
                const float s = ks ? sb : sa;
                uint4 v = *(const uint4*)src;
                u16 e[8]; *(uint4*)e = v;
                #pragma unroll
                for (int q = 0; q < 8; q++) o[q] = f2b(b2f(e[q]) * s);
            }
            Qf[t][ks] = *(bf16x8*)o;
        }
    }

    const int s_jj = tid >> 3, s_ch = tid & 7;
    const u16* s_src = ((s_ch >> 2) ? Qp : Kp) + rbp + (s_ch & 3) * 8;
    const int v_j = tid & 63, v_d0 = (tid >> 6) * 4;

    {
        int j = s_jj;
        uint4 kv = (j < PLc) ? *(const uint4*)(s_src + (size_t)j * 256) : make_uint4(0,0,0,0);
        uint2 vv = (v_j < PLc) ? *(const uint2*)(Vp + rbp + (size_t)v_j * 256 + v_d0) : make_uint2(0,0);
        *(uint4*)&Ks[0][sw(s_jj, s_ch * 8, 64)] = kv;
        u16 e[4]; *(uint2*)e = vv;
        #pragma unroll
        for (int q = 0; q < 4; q++) U.s1.VpT[0][sw(v_d0 + q, v_j, 64)] = e[q];
    }
    __syncthreads();

    float rs[3] = {0.f, 0.f, 0.f};
    f32x4 accd[3][2] = {};
    for (int jt = 0; jt < 16; jt++) {
        const int cur = jt & 1, j0 = jt * 64;
        const int jn = j0 + 64 + s_jj;
        uint4 kv = (jn < PLc) ? *(const uint4*)(s_src + (size_t)jn * 256) : make_uint4(0,0,0,0);
        const int vn = j0 + 64 + v_j;
        uint2 vv = (vn < PLc) ? *(const uint2*)(Vp + rbp + (size_t)vn * 256 + v_d0) : make_uint2(0,0);

        bf16x8 kf[4][2];
        #pragma unroll
        for (int js = 0; js < 4; js++)
            #pragma unroll
            for (int ks = 0; ks < 2; ks++)
                kf[js][ks] = *(const bf16x8*)&Ks[cur][sw(js * 16 + ln, ks * 32 + g * 8, 64)];

        #pragma unroll
        for (int t = 0; t < 3; t++) {
            if (t >= nmt) break;
            const int mt = mtsA[t];
            f32x4 acc[4] = {};
            #pragma unroll
            for (int ks = 0; ks < 2; ks++)
                #pragma unroll
                for (int js = 0; js < 4; js++)
                    acc[js] = __builtin_amdgcn_mfma_f32_16x16x32_bf16(kf[js][ks], Qf[t][ks], acc[js], 0, 0, 0);
            const int irow = mt * 16 + ln;
            #pragma unroll
            for (int js = 0; js < 4; js++) {
                u16 pb[4];
                float psum = 0.f;
                #pragma unroll
                for (int r = 0; r < 4; r++) {
                    float p = __expf(acc[js][r]);
                    psum += p;
                    pb[r] = f2b(p);
                }
                rs[t] += psum;
                *(ushort4*)&U.s1.Pm[sw(irow, js * 16 + g * 4, 64)] = *(ushort4*)pb;
            }
        }
        // ctx_d accumulate (swapped operands: D row -> d, col -> i)
        #pragma unroll
        for (int t = 0; t < 3; t++) {
            if (t >= nmt) break;
            const int mt = mtsA[t];
            #pragma unroll
            for (int ks2 = 0; ks2 < 2; ks2++) {
                bf16x8 af = *(const bf16x8*)&U.s1.Pm[sw(mt * 16 + ln, ks2 * 32 + g * 8, 64)];
                #pragma unroll
                for (int nd = 0; nd < 2; nd++) {
                    bf16x8 bv = *(const bf16x8*)&U.s1.VpT[cur][sw(nd * 16 + ln, ks2 * 32 + g * 8, 64)];
                    accd[t][nd] = __builtin_amdgcn_mfma_f32_16x16x32_bf16(bv, af, accd[t][nd], 0, 0, 0);
                }
            }
        }
        *(uint4*)&Ks[cur ^ 1][sw(s_jj, s_ch * 8, 64)] = kv;
        {
            u16 e[4]; *(uint2*)e = vv;
            #pragma unroll
            for (int q = 0; q < 4; q++) U.s1.VpT[cur ^ 1][sw(v_d0 + q, v_j, 64)] = e[q];
        }
        __syncthreads();
    }

    #pragma unroll
    for (int t = 0; t < 3; t++) {
        float v = rs[t];
        v += __shfl_xor(v, 16);
        v += __shfl_xor(v, 32);
        rs[t] = v;
    }
    if (g == 0) {
        #pragma unroll
        for (int t = 0; t < 3; t++) {
            if (t >= nmt) break;
            const int i = mtsA[t] * 16 + ln;
            r_l[i] = (i < DLn) ? 1.0f / (rs[t] - 24.0f) : 0.0f;
        }
    }
    __syncthreads();

    // ---- ctx_d write: thread owns row i = mt*16+ln, cols nd*16 + g*4 .. +3 ----
    #pragma unroll
    for (int t = 0; t < 3; t++) {
        if (t >= nmt) break;
        const int i = mtsA[t] * 16 + ln;
        if (i < DLn) {
            const float ri = r_l[i];
            #pragma unroll
            for (int nd = 0; nd < 2; nd++) {
                u16 o[4];
                #pragma unroll
                for (int r = 0; r < 4; r++) o[r] = f2b(accd[t][nd][r] * ri);
                *(uint2*)&ctx_d[rbd + (size_t)i * 256 + nd * 16 + g * 4] = *(uint2*)o;
            }
        }
    }
    for (int c = tid; c < 320 * 8; c += 512) {
        const int i = c >> 3, d0 = (c & 7) * 4;
        u16 o[4] = {0,0,0,0};
        if (i < DLn) {
            const float ri = r_l[i];
            uint2 v = *(const uint2*)(Vd + rbd + (size_t)i * 256 + d0);
            u16 e[4]; *(uint2*)e = v;
            #pragma unroll
            for (int q = 0; q < 4; q++) o[q] = f2b(b2f(e[q]) * ri);
        }
        #pragma unroll
        for (int q = 0; q < 4; q++) U.s2.VdT[sw(d0 + q, i, 320)] = o[q];
    }
    {
        int j = s_jj;
        uint4 kv = (j < PLc) ? *(const uint4*)(s_src + (size_t)j * 256) : make_uint4(0,0,0,0);
        *(uint4*)&Ks[0][sw(s_jj, s_ch * 8, 64)] = kv;
    }
    float rr[3][4];
    #pragma unroll
    for (int t = 0; t < 3; t++)
        #pragma unroll
        for (int r = 0; r < 4; r++)
            rr[t][r] = (t < nmt) ? r_l[mtsA[t] * 16 + g * 4 + r] : 0.0f;
    __syncthreads();

    for (int jt = 0; jt < 16; jt++) {
        const int cur = jt & 1, j0 = jt * 64;
        const int jn = j0 + 64 + s_jj;
        uint4 kv = (jn < PLc) ? *(const uint4*)(s_src + (size_t)jn * 256) : make_uint4(0,0,0,0);

        bf16x8 kf[4][2];
        #pragma unroll
        for (int js = 0; js < 4; js++)
            #pragma unroll
            for (int ks = 0; ks < 2; ks++)
                kf[js][ks] = *(const bf16x8*)&Ks[cur][sw(js * 16 + ln, ks * 32 + g * 8, 64)];

        float csl[4] = {0.f, 0.f, 0.f, 0.f};
        #pragma unroll
        for (int t = 0; t < 3; t++) {
            if (t >= nmt) break;
            const int mt = mtsA[t];
            f32x4 acc[4] = {};
            #pragma unroll
            for (int ks = 0; ks < 2; ks++)
                #pragma unroll
                for (int js = 0; js < 4; js++)
                    acc[js] = __builtin_amdgcn_mfma_f32_16x16x32_bf16(Qf[t][ks], kf[js][ks], acc[js], 0, 0, 0);
            #pragma unroll
            for (int js = 0; js < 4; js++) {
                u16 pb[4];
                #pragma unroll
                for (int r = 0; r < 4; r++) {
                    float p = __expf(acc[js][r]);
                    csl[js] += p * rr[t][r];
                    pb[r] = f2b(p);
                }
                *(ushort4*)&U.s2.PT[sw(js * 16 + ln, mt * 16 + g * 4, 320)] = *(ushort4*)pb;
            }
        }
        #pragma unroll
        for (int js = 0; js < 4; js++) {
            float v = csl[js];
            v += __shfl_xor(v, 16);
            v += __shfl_xor(v, 32);
            csl[js] = v;
        }
        if (g == 0) {
            #pragma unroll
            for (int js = 0; js < 4; js++) colpart[w][js * 16 + ln] = csl[js];
        }
        *(uint4*)&Ks[cur ^ 1][sw(s_jj, s_ch * 8, 64)] = kv;
        __syncthreads();

        // ctx_p tile (swapped operands: thread owns row j, cols ds2*16+g*4..+3)
        {
            const int js2 = w & 3, ds2 = w >> 2;
            f32x4 ap = {};
            #pragma unroll
            for (int k = 0; k < 10; k++) {
                bf16x8 af = *(const bf16x8*)&U.s2.PT[sw(js2 * 16 + ln, k * 32 + g * 8, 320)];
                bf16x8 bv = *(const bf16x8*)&U.s2.VdT[sw(ds2 * 16 + ln, k * 32 + g * 8, 320)];
                ap = __builtin_amdgcn_mfma_f32_16x16x32_bf16(bv, af, ap, 0, 0, 0);
            }
            const int j = j0 + js2 * 16 + ln;
            if (j < PLc) {
                u16 o[4];
                #pragma unroll
                for (int r = 0; r < 4; r++) o[r] = f2b(ap[r]);
                *(uint2*)&ctx_p[rbp + (size_t)j * 256 + ds2 * 16 + g * 4] = *(uint2*)o;
            }
        }
        if (w == 0) {
            float tot = 0.f;
            #pragma unroll
            for (int ww = 0; ww < 8; ww++) tot += colpart[ww][lane];
            const int j = j0 + lane;
            if (j < PLc) cm[(size_t)(b * PLc + j) * 8 + h] = tot * (1.0f / 290.0f);
        }
        __syncthreads();
    }
}

// ---------------- final combine, 4 cols/thread ----------------
__global__ __launch_bounds__(256) void combine_kernel(
        const float* __restrict__ drug, const float* __restrict__ prot,
        const float* __restrict__ scale_d, const float* __restrict__ scale_p,
        const float* __restrict__ pe,
        const u16* __restrict__ Xd, const u16* __restrict__ Xp,
        const u16* __restrict__ gate_d, const u16* __restrict__ gate_p,
        const float* __restrict__ cm,
        const float* __restrict__ w_fc_dp, const float* __restrict__ b_fc_dp,
        const float* __restrict__ w_fc_pd, const float* __restrict__ b_fc_pd,
        float* __restrict__ out) {
    int idx = blockIdx.x * 256 + threadIdx.x;
    int r = idx >> 6, c4 = (idx & 63) * 4;
    if (r < MD) {
        int b = r / DLn, i = r % DLn;
        float s = scale_d[0];
        float4 dv = *(const float4*)&drug[(size_t)r * 256 + c4];
        float4 pv = *(const float4*)&pe[i * 256 + c4];
        uint2 xv = *(const uint2*)&Xd[(size_t)r * 256 + c4];
        uint2 gv = *(const uint2*)&gate_d[(size_t)r * 256 + c4];
        float4 bb = *(const float4*)&b_fc_dp[c4];
        float da[4] = { bb.x, bb.y, bb.z, bb.w };
        #pragma unroll
        for (int hh = 0; hh < 8; hh++) {
            float4 wv = *(const float4*)&w_fc_dp[hh * 256 + c4];
            da[0] += 0.001f * wv.x; da[1] += 0.001f * wv.y;
            da[2] += 0.001f * wv.z; da[3] += 0.001f * wv.w;
        }
        u16 xe[4]; *(uint2*)xe = xv;
        u16 ge[4]; *(uint2*)ge = gv;
        float e0 = dv.x + s * pv.x, e1 = dv.y + s * pv.y;
        float e2 = dv.z + s * pv.z, e3 = dv.w + s * pv.w;
        float4 o;
        o.x = e0 + b2f(xe[0]) * b2f(ge[0]) * sigm(da[0]);
        o.y = e1 + b2f(xe[1]) * b2f(ge[1]) * sigm(da[1]);
        o.z = e2 + b2f(xe[2]) * b2f(ge[2]) * sigm(da[2]);
        o.w = e3 + b2f(xe[3]) * b2f(ge[3]) * sigm(da[3]);
        *(float4*)&out[((size_t)b * 1290 + i) * 256 + c4] = o;
    } else {
        int rr = r - MD;
        int b = rr / PLc, j = rr % PLc;
        float s = scale_p[0];
        float4 dv = *(const float4*)&prot[(size_t)rr * 256 + c4];
        float4 pv = *(const float4*)&pe[j * 256 + c4];
        uint2 xv = *(const uint2*)&Xp[(size_t)rr * 256 + c4];
        uint2 gv = *(const uint2*)&gate_p[(size_t)rr * 256 + c4];
        float4 bb = *(const float4*)&b_fc_pd[c4];
        float pa[4] = { bb.x, bb.y, bb.z, bb.w };
        #pragma unroll
        for (int hh = 0; hh < 8; hh++) {
            float cmh = cm[(size_t)rr * 8 + hh];
            float4 wv = *(const float4*)&w_fc_pd[hh * 256 + c4];
            pa[0] += cmh * wv.x; pa[1] += cmh * wv.y;
            pa[2] += cmh * wv.z; pa[3] += cmh * wv.w;
        }
        u16 xe[4]; *(uint2*)xe = xv;
        u16 ge[4]; *(uint2*)ge = gv;
        float e0 = dv.x + s * pv.x, e1 = dv.y + s * pv.y;
        float e2 = dv.z + s * pv.z, e3 = dv.w + s * pv.w;
        float4 o;
        o.x = e0 + b2f(xe[0]) * b2f(ge[0]) * sigm(pa[0]);
        o.y = e1 + b2f(xe[1]) * b2f(ge[1]) * sigm(pa[1]);
        o.z = e2 + b2f(xe[2]) * b2f(ge[2]) * sigm(pa[2]);
        o.w = e3 + b2f(xe[3]) * b2f(ge[3]) * sigm(pa[3]);
        *(float4*)&out[((size_t)b * 1290 + 290 + j) * 256 + c4] = o;
    }
}

extern "C" void kernel_launch(void* const* d_in, const int* in_sizes, int n_in,
                              void* d_out, int out_size, void* d_ws, size_t ws_size,
                              hipStream_t stream) {
    (void)in_sizes; (void)n_in; (void)out_size;
    const float* drug    = (const float*)d_in[0];
    const float* prot    = (const float*)d_in[1];
    const float* scale_d = (const float*)d_in[2];
    const float* scale_p = (const float*)d_in[3];

    char* ws = (char*)d_ws;
    size_t off = 0;
    auto alloc = [&](size_t bytes) -> void* {
        void* p = ws + off;
        off += (bytes + 255) & ~(size_t)255;
        return p;
    };
    float* pe   = (float*)alloc((size_t)1000 * 256 * 4);
    u16* wt     = (u16*)alloc((size_t)10 * 65536 * 2);
    u16* Qd     = (u16*)alloc((size_t)MD * 256 * 2);
    u16* Kd     = (u16*)alloc((size_t)MD * 256 * 2);
    u16* Vd     = (u16*)alloc((size_t)MD * 256 * 2);
    u16* gate_d = (u16*)alloc((size_t)MD * 256 * 2);
    u16* Kp     = (u16*)alloc((size_t)MP * 256 * 2);
    u16* Vp     = (u16*)alloc((size_t)MP * 256 * 2);
    u16* Qp     = (u16*)alloc((size_t)MP * 256 * 2);
    u16* gate_p = (u16*)alloc((size_t)MP * 256 * 2);
    u16* ctxd   = (u16*)alloc((size_t)MD * 256 * 2);
    u16* ctxp   = (u16*)alloc((size_t)MP * 256 * 2);
    float* cm   = (float*)alloc((size_t)MP * 8 * 4);
    u16* Xd     = (u16*)alloc((size_t)MD * 256 * 2);
    u16* Xp     = (u16*)alloc((size_t)MP * 256 * 2);
    if (off > ws_size) return;

    pe_kernel<<<1000, 256, 0, stream>>>(pe);

    WPtrs wp;
    const int wsrc[10] = {4, 12, 14, 25, 6, 8, 10, 27, 16, 18};
    for (int m = 0; m < 10; m++) wp.w[m] = (const float*)d_in[wsrc[m]];
    wprep_kernel<<<dim3(16, 10), 256, 0, stream>>>(wp, wt);

    auto W = [&](int slot) { return wt + (size_t)slot * 65536; };

    PCfg2 p1;
    p1.split = 145;
    p1.c0 = { nullptr, drug, scale_d, pe, DLn,
              { { W(0), (const float*)d_in[5],  Qd,     0 },
                { W(1), (const float*)d_in[13], Kd,     0 },
                { W(2), (const float*)d_in[15], Vd,     0 },
                { W(3), (const float*)d_in[26], gate_d, 1 } } };
    p1.c1 = { nullptr, prot, scale_p, pe, PLc,
              { { W(4), (const float*)d_in[7],  Kp,     0 },
                { W(5), (const float*)d_in[9],  Vp,     0 },
                { W(6), (const float*)d_in[11], Qp,     0 },
                { W(7), (const float*)d_in[28], gate_p, 1 } } };
    proj_kernel<4><<<645, 256, 0, stream>>>(p1);

    attn_kernel<<<256, 512, 0, stream>>>(Qd, Kd, Vd, Kp, Vp, Qp,
                                         (const float*)d_in[20], ctxd, ctxp, cm);

    PCfg2 p2;
    p2.split = 145;
    p2.c0 = { ctxd, nullptr, nullptr, nullptr, DLn,
              { { W(8), (const float*)d_in[17], Xd, 0 }, {}, {}, {} } };
    p2.c1 = { ctxp, nullptr, nullptr, nullptr, PLc,
              { { W(9), (const float*)d_in[19], Xp, 0 }, {}, {}, {} } };
    proj_kernel<1><<<645, 256, 0, stream>>>(p2);

    combine_kernel<<<(MD + MP) / 4, 256, 0, stream>>>(drug, prot, scale_d, scale_p, pe,
        Xd, Xp, gate_d, gate_p, cm,
        (const float*)d_in[21], (const float*)d_in[22],
        (const float*)d_in[23], (const float*)d_in[24],
        (float*)d_out);
}

// Round 8
// 264.493 us; speedup vs baseline: 1.2426x; 1.0032x over previous
//
#include <hip/hip_runtime.h>
#include <math.h>

typedef __attribute__((ext_vector_type(8))) short bf16x8;
typedef __attribute__((ext_vector_type(4))) float f32x4;
typedef unsigned short u16;
typedef unsigned int u32;

#define DEVFN static __device__ __forceinline__

constexpr int NB  = 32;
constexpr int DLn = 290;
constexpr int PLc = 1000;
constexpr int MD  = NB * DLn;   // 9280  = 145*64
constexpr int MP  = NB * PLc;   // 32000 = 500*64

DEVFN u16 f2b(float f) {
    u32 u = __builtin_bit_cast(u32, f);
    u32 r = u + 0x7fffu + ((u >> 16) & 1u);
    return (u16)(r >> 16);
}
DEVFN float b2f(u16 s) { return __builtin_bit_cast(float, (u32)s << 16); }
DEVFN float sigm(float x) { return 1.0f / (1.0f + __expf(-x)); }
// XOR-swizzled LDS index (u16 units); stride multiple of 8 u16. 16B-aligned.
DEVFN int sw(int row, int col, int stride) { return row * stride + (col ^ ((row & 7) << 3)); }

// ---------------- PE table ----------------
__global__ void pe_kernel(float* __restrict__ pe) {
    int p = blockIdx.x, c = threadIdx.x;
    float div = __expf((float)(c & ~1) * (-9.210340371976184f / 256.0f));
    float ang = (float)p * div;
    pe[p * 256 + c] = (c & 1) ? cosf(ang) : sinf(ang);
}

// ---------------- weight prep: WT[n][k] bf16, LDS transpose ----------------
struct WPtrs { const float* w[10]; };
__global__ __launch_bounds__(256) void wprep_kernel(WPtrs wp, u16* __restrict__ wt) {
    __shared__ u16 t[64][66];
    int m = blockIdx.y, tile = blockIdx.x;
    int k0 = (tile >> 2) * 64, n0 = (tile & 3) * 64;
    const float* w = wp.w[m];
    int r = threadIdx.x >> 6, c = threadIdx.x & 63;
    #pragma unroll
    for (int q = 0; q < 16; q++) {
        int rr = r + q * 4;
        t[rr][c] = f2b(w[(size_t)(k0 + rr) * 256 + n0 + c]);
    }
    __syncthreads();
    #pragma unroll
    for (int q = 0; q < 16; q++) {
        int rr = r + q * 4;
        wt[((size_t)m << 16) + (size_t)(n0 + rr) * 256 + k0 + c] = t[c][rr];
    }
}

// ---------------- fused projection ----------------
// One block per 64-row A strip; A fragments in registers (once). B streamed via
// double-buffered swizzled LDS. Swapped-operand MFMA -> each thread owns one C
// row and 16 consecutive cols -> 2x uint4 stores. ALL config fields selected
// via uniform scalar ternaries on STATIC member accesses (s_cselect, no scratch).
struct PM { const u16* BT; const float* bias; u16* C; int sig; };
struct PCfg {
    const u16* Ab;
    const float* Af32;
    const float* scale;
    const float* pe;
    int plen;
    PM m[4];
};
struct PCfg2 { PCfg c0, c1; int split; };

template<int NMAT>
__global__ __launch_bounds__(256, 2) void proj_kernel(PCfg2 cfgs) {
    const int bid = blockIdx.x;
    const bool f1 = bid < cfgs.split;
    const int mt = f1 ? bid : bid - cfgs.split;

    // uniform per-block field selects -- static member accesses only
    const u16*   Ab    = f1 ? cfgs.c0.Ab    : cfgs.c1.Ab;
    const float* Af32  = f1 ? cfgs.c0.Af32  : cfgs.c1.Af32;
    const float* scale = f1 ? cfgs.c0.scale : cfgs.c1.scale;
    const float* pe    = f1 ? cfgs.c0.pe    : cfgs.c1.pe;
    const int    plen  = f1 ? cfgs.c0.plen  : cfgs.c1.plen;
    const u16*   BT0   = f1 ? cfgs.c0.m[0].BT   : cfgs.c1.m[0].BT;
    const float* bias_0= f1 ? cfgs.c0.m[0].bias : cfgs.c1.m[0].bias;
    u16*         C0    = f1 ? cfgs.c0.m[0].C    : cfgs.c1.m[0].C;
    const int    sig0  = f1 ? cfgs.c0.m[0].sig  : cfgs.c1.m[0].sig;
    const u16*   BT1   = f1 ? cfgs.c0.m[1].BT   : cfgs.c1.m[1].BT;
    const float* bias_1= f1 ? cfgs.c0.m[1].bias : cfgs.c1.m[1].bias;
    u16*         C1    = f1 ? cfgs.c0.m[1].C    : cfgs.c1.m[1].C;
    const int    sig1  = f1 ? cfgs.c0.m[1].sig  : cfgs.c1.m[1].sig;
    const u16*   BT2   = f1 ? cfgs.c0.m[2].BT   : cfgs.c1.m[2].BT;
    const float* bias_2= f1 ? cfgs.c0.m[2].bias : cfgs.c1.m[2].bias;
    u16*         C2    = f1 ? cfgs.c0.m[2].C    : cfgs.c1.m[2].C;
    const int    sig2  = f1 ? cfgs.c0.m[2].sig  : cfgs.c1.m[2].sig;
    const u16*   BT3   = f1 ? cfgs.c0.m[3].BT   : cfgs.c1.m[3].BT;
    const float* bias_3= f1 ? cfgs.c0.m[3].bias : cfgs.c1.m[3].bias;
    u16*         C3    = f1 ? cfgs.c0.m[3].C    : cfgs.c1.m[3].C;
    const int    sig3  = f1 ? cfgs.c0.m[3].sig  : cfgs.c1.m[3].sig;

    // mi is a compile-time constant at each use (fully unrolled loops) -> folds
    #define SEL_BT(mi)   ((mi) == 0 ? BT0   : (mi) == 1 ? BT1   : (mi) == 2 ? BT2   : BT3)
    #define SEL_BIAS(mi) ((mi) == 0 ? bias_0: (mi) == 1 ? bias_1: (mi) == 2 ? bias_2: bias_3)
    #define SEL_C(mi)    ((mi) == 0 ? C0    : (mi) == 1 ? C1    : (mi) == 2 ? C2    : C3)
    #define SEL_SIG(mi)  ((mi) == 0 ? sig0  : (mi) == 1 ? sig1  : (mi) == 2 ? sig2  : sig3)

    __shared__ u16 Bs[2][64 * 256];
    const int tid = threadIdx.x;
    const int lane = tid & 63, w = tid >> 6, ln = lane & 15, g = lane >> 4;

    // ---- A fragments in registers: row mt*64 + w*16 + ln, k = ks*32 + g*8 ----
    bf16x8 Af[8];
    {
        const int row = mt * 64 + w * 16 + ln;
        if (Af32) {
            const int i = row % plen;
            const float s = scale[0];
            const float* Xp_ = Af32 + (size_t)row * 256 + g * 8;
            const float* Pe_ = pe + (size_t)i * 256 + g * 8;
            #pragma unroll
            for (int ks = 0; ks < 8; ks++) {
                float4 xa = *(const float4*)(Xp_ + ks * 32);
                float4 xb = *(const float4*)(Xp_ + ks * 32 + 4);
                float4 pa = *(const float4*)(Pe_ + ks * 32);
                float4 pb = *(const float4*)(Pe_ + ks * 32 + 4);
                u16 o[8];
                o[0] = f2b(xa.x + s * pa.x); o[1] = f2b(xa.y + s * pa.y);
                o[2] = f2b(xa.z + s * pa.z); o[3] = f2b(xa.w + s * pa.w);
                o[4] = f2b(xb.x + s * pb.x); o[5] = f2b(xb.y + s * pb.y);
                o[6] = f2b(xb.z + s * pb.z); o[7] = f2b(xb.w + s * pb.w);
                Af[ks] = *(bf16x8*)o;
            }
        } else {
            const u16* Ap = Ab + (size_t)row * 256 + g * 8;
            #pragma unroll
            for (int ks = 0; ks < 8; ks++)
                Af[ks] = *(const bf16x8*)(Ap + ks * 32);
        }
    }

    // staging: slot lr holds BT row (chunk*64 + nu(lr)); bit-permutation nu makes
    // the swapped-MFMA output columns consecutive per thread.
    const int lr = tid >> 2, lc = tid & 3;
    const int nu = ((lr >> 5) & 1) * 32 + ((lr >> 2) & 3) * 8 + ((lr >> 4) & 1) * 4 + (lr & 3);

    // prologue: stage (matrix 0, chunk 0)
    {
        const u16* Bp = BT0 + (size_t)nu * 256 + lc * 8;
        uint4 bv[8];
        #pragma unroll
        for (int kk = 0; kk < 8; kk++) bv[kk] = *(const uint4*)(Bp + kk * 32);
        #pragma unroll
        for (int kk = 0; kk < 8; kk++) *(uint4*)&Bs[0][sw(lr, lc * 8 + kk * 32, 256)] = bv[kk];
    }
    __syncthreads();

    #pragma unroll
    for (int mi = 0; mi < NMAT; mi++) {
        #pragma unroll
        for (int c = 0; c < 4; c++) {
            const int ph = mi * 4 + c, cur = ph & 1;
            constexpr int NPH = NMAT * 4;
            const bool hasNext = (ph + 1 < NPH);
            uint4 bv[8];
            if (hasNext) {
                const int nmi = (ph + 1) >> 2, nc = (ph + 1) & 3;
                const u16* Bp = SEL_BT(nmi) + (size_t)(nc * 64 + nu) * 256 + lc * 8;
                #pragma unroll
                for (int kk = 0; kk < 8; kk++) bv[kk] = *(const uint4*)(Bp + kk * 32);
            }
            // compute: D = Bfrag * Afrag  (C^T fragment)
            f32x4 acc[4] = {};
            #pragma unroll
            for (int ks = 0; ks < 8; ks++) {
                #pragma unroll
                for (int nt = 0; nt < 4; nt++) {
                    bf16x8 bf = *(const bf16x8*)&Bs[cur][sw(nt * 16 + ln, ks * 32 + g * 8, 256)];
                    acc[nt] = __builtin_amdgcn_mfma_f32_16x16x32_bf16(bf, Af[ks], acc[nt], 0, 0, 0);
                }
            }
            // epilogue: thread owns row mt*64+w*16+ln, 16 consecutive cols (2 x 16B)
            {
                const float* bias = SEL_BIAS(mi);
                u16* C = SEL_C(mi);
                const int sig = SEL_SIG(mi);
                const int row = mt * 64 + w * 16 + ln;
                const int base0 = c * 64 + g * 8, base1 = base0 + 32;
                f32x4 b0 = *(const f32x4*)&bias[base0];
                f32x4 b1 = *(const f32x4*)&bias[base0 + 4];
                f32x4 b2 = *(const f32x4*)&bias[base1];
                f32x4 b3 = *(const f32x4*)&bias[base1 + 4];
                float v[16];
                #pragma unroll
                for (int t = 0; t < 4; t++) {
                    v[t]      = acc[0][t] + b0[t];
                    v[4 + t]  = acc[1][t] + b1[t];
                    v[8 + t]  = acc[2][t] + b2[t];
                    v[12 + t] = acc[3][t] + b3[t];
                }
                if (sig) {
                    #pragma unroll
                    for (int t = 0; t < 16; t++) v[t] = sigm(v[t]);
                }
                u16 o[16];
                #pragma unroll
                for (int t = 0; t < 16; t++) o[t] = f2b(v[t]);
                u16* Cp = C + (size_t)row * 256;
                *(uint4*)&Cp[base0] = *(uint4*)&o[0];
                *(uint4*)&Cp[base1] = *(uint4*)&o[8];
            }
            __syncthreads();
            if (hasNext) {
                #pragma unroll
                for (int kk = 0; kk < 8; kk++) *(uint4*)&Bs[cur ^ 1][sw(lr, lc * 8 + kk * 32, 256)] = bv[kk];
            }
            __syncthreads();
        }
    }
    #undef SEL_BT
    #undef SEL_BIAS
    #undef SEL_C
    #undef SEL_SIG
}

// ---------------- attention: one block per (b,h), no-max softmax, 2 sweeps ----------------
__global__ __launch_bounds__(512) void attn_kernel(
        const u16* __restrict__ Qd, const u16* __restrict__ Kd, const u16* __restrict__ Vd,
        const u16* __restrict__ Kp, const u16* __restrict__ Vp, const u16* __restrict__ Qp,
        const float* __restrict__ alpha,
        u16* __restrict__ ctx_d, u16* __restrict__ ctx_p, float* __restrict__ cm) {
    __shared__ u16 Ks[2][64 * 64];
    __shared__ union {
        struct { u16 VpT[2][32 * 64]; u16 Pm[320 * 64]; } s1;
        struct { u16 PT[64 * 320]; u16 VdT[32 * 320]; } s2;
    } U;
    __shared__ float r_l[320];
    __shared__ float colpart[8][64];

    const int bh = blockIdx.x, b = bh >> 3, h = bh & 7;
    const int tid = threadIdx.x;
    const int w = tid >> 6, lane = tid & 63, ln = lane & 15, g = lane >> 4;

    const float a = sigm(alpha[0]);
    const float inv = 0.1767766952966369f;
    const float sa = a * inv, sb = (1.0f - a) * inv;
    const int nmt = (w < 4) ? 3 : 2;
    const int mtsA[3] = { w, w + 8, w + 16 };

    const size_t rbd = (size_t)b * DLn * 256 + h * 32;
    const size_t rbp = (size_t)b * PLc * 256 + h * 32;

    bf16x8 Qf[3][2];
    #pragma unroll
    for (int t = 0; t < 3; t++) {
        const int i = mtsA[t] * 16 + ln;
        #pragma unroll
        for (int ks = 0; ks < 2; ks++) {
            u16 o[8] = {0,0,0,0,0,0,0,0};
            if (t < nmt && i < DLn) {
                const u16* src = (ks ? Kd : Qd) + rbd + (size_t)i * 256 + g * 8;
                const float s = ks ? sb : sa;
                uint4 v = *(const uint4*)src;
                u16 e[8]; *(uint4*)e = v;
                #pragma unroll
                for (int q = 0; q < 8; q++) o[q] = f2b(b2f(e[q]) * s);
            }
            Qf[t][ks] = *(bf16x8*)o;
        }
    }

    const int s_jj = tid >> 3, s_ch = tid & 7;
    const u16* s_src = ((s_ch >> 2) ? Qp : Kp) + rbp + (s_ch & 3) * 8;
    const int v_j = tid & 63, v_d0 = (tid >> 6) * 4;

    {
        int j = s_jj;
        uint4 kv = (j < PLc) ? *(const uint4*)(s_src + (size_t)j * 256) : make_uint4(0,0,0,0);
        uint2 vv = (v_j < PLc) ? *(const uint2*)(Vp + rbp + (size_t)v_j * 256 + v_d0) : make_uint2(0,0);
        *(uint4*)&Ks[0][sw(s_jj, s_ch * 8, 64)] = kv;
        u16 e[4]; *(uint2*)e = vv;
        #pragma unroll
        for (int q = 0; q < 4; q++) U.s1.VpT[0][sw(v_d0 + q, v_j, 64)] = e[q];
    }
    __syncthreads();

    float rs[3] = {0.f, 0.f, 0.f};
    f32x4 accd[3][2] = {};
    for (int jt = 0; jt < 16; jt++) {
        const int cur = jt & 1, j0 = jt * 64;
        const int jn = j0 + 64 + s_jj;
        uint4 kv = (jn < PLc) ? *(const uint4*)(s_src + (size_t)jn * 256) : make_uint4(0,0,0,0);
        const int vn = j0 + 64 + v_j;
        uint2 vv = (vn < PLc) ? *(const uint2*)(Vp + rbp + (size_t)vn * 256 + v_d0) : make_uint2(0,0);

        bf16x8 kf[4][2];
        #pragma unroll
        for (int js = 0; js < 4; js++)
            #pragma unroll
            for (int ks = 0; ks < 2; ks++)
                kf[js][ks] = *(const bf16x8*)&Ks[cur][sw(js * 16 + ln, ks * 32 + g * 8, 64)];

        #pragma unroll
        for (int t = 0; t < 3; t++) {
            if (t >= nmt) break;
            const int mt = mtsA[t];
            f32x4 acc[4] = {};
            #pragma unroll
            for (int ks = 0; ks < 2; ks++)
                #pragma unroll
                for (int js = 0; js < 4; js++)
                    acc[js] = __builtin_amdgcn_mfma_f32_16x16x32_bf16(kf[js][ks], Qf[t][ks], acc[js], 0, 0, 0);
            const int irow = mt * 16 + ln;
            #pragma unroll
            for (int js = 0; js < 4; js++) {
                u16 pb[4];
                float psum = 0.f;
                #pragma unroll
                for (int r = 0; r < 4; r++) {
                    float p = __expf(acc[js][r]);
                    psum += p;
                    pb[r] = f2b(p);
                }
                rs[t] += psum;
                *(ushort4*)&U.s1.Pm[sw(irow, js * 16 + g * 4, 64)] = *(ushort4*)pb;
            }
        }
        // ctx_d accumulate (swapped operands: D row -> d, col -> i)
        #pragma unroll
        for (int t = 0; t < 3; t++) {
            if (t >= nmt) break;
            const int mt = mtsA[t];
            #pragma unroll
            for (int ks2 = 0; ks2 < 2; ks2++) {
                bf16x8 af = *(const bf16x8*)&U.s1.Pm[sw(mt * 16 + ln, ks2 * 32 + g * 8, 64)];
                #pragma unroll
                for (int nd = 0; nd < 2; nd++) {
                    bf16x8 bv = *(const bf16x8*)&U.s1.VpT[cur][sw(nd * 16 + ln, ks2 * 32 + g * 8, 64)];
                    accd[t][nd] = __builtin_amdgcn_mfma_f32_16x16x32_bf16(bv, af, accd[t][nd], 0, 0, 0);
                }
            }
        }
        *(uint4*)&Ks[cur ^ 1][sw(s_jj, s_ch * 8, 64)] = kv;
        {
            u16 e[4]; *(uint2*)e = vv;
            #pragma unroll
            for (int q = 0; q < 4; q++) U.s1.VpT[cur ^ 1][sw(v_d0 + q, v_j, 64)] = e[q];
        }
        __syncthreads();
    }

    #pragma unroll
    for (int t = 0; t < 3; t++) {
        float v = rs[t];
        v += __shfl_xor(v, 16);
        v += __shfl_xor(v, 32);
        rs[t] = v;
    }
    if (g == 0) {
        #pragma unroll
        for (int t = 0; t < 3; t++) {
            if (t >= nmt) break;
            const int i = mtsA[t] * 16 + ln;
            r_l[i] = (i < DLn) ? 1.0f / (rs[t] - 24.0f) : 0.0f;
        }
    }
    __syncthreads();

    // ---- ctx_d write: thread owns row i = mt*16+ln, cols nd*16 + g*4 .. +3 ----
    #pragma unroll
    for (int t = 0; t < 3; t++) {
        if (t >= nmt) break;
        const int i = mtsA[t] * 16 + ln;
        if (i < DLn) {
            const float ri = r_l[i];
            #pragma unroll
            for (int nd = 0; nd < 2; nd++) {
                u16 o[4];
                #pragma unroll
                for (int r = 0; r < 4; r++) o[r] = f2b(accd[t][nd][r] * ri);
                *(uint2*)&ctx_d[rbd + (size_t)i * 256 + nd * 16 + g * 4] = *(uint2*)o;
            }
        }
    }
    for (int c = tid; c < 320 * 8; c += 512) {
        const int i = c >> 3, d0 = (c & 7) * 4;
        u16 o[4] = {0,0,0,0};
        if (i < DLn) {
            const float ri = r_l[i];
            uint2 v = *(const uint2*)(Vd + rbd + (size_t)i * 256 + d0);
            u16 e[4]; *(uint2*)e = v;
            #pragma unroll
            for (int q = 0; q < 4; q++) o[q] = f2b(b2f(e[q]) * ri);
        }
        #pragma unroll
        for (int q = 0; q < 4; q++) U.s2.VdT[sw(d0 + q, i, 320)] = o[q];
    }
    {
        int j = s_jj;
        uint4 kv = (j < PLc) ? *(const uint4*)(s_src + (size_t)j * 256) : make_uint4(0,0,0,0);
        *(uint4*)&Ks[0][sw(s_jj, s_ch * 8, 64)] = kv;
    }
    float rr[3][4];
    #pragma unroll
    for (int t = 0; t < 3; t++)
        #pragma unroll
        for (int r = 0; r < 4; r++)
            rr[t][r] = (t < nmt) ? r_l[mtsA[t] * 16 + g * 4 + r] : 0.0f;
    __syncthreads();

    for (int jt = 0; jt < 16; jt++) {
        const int cur = jt & 1, j0 = jt * 64;
        const int jn = j0 + 64 + s_jj;
        uint4 kv = (jn < PLc) ? *(const uint4*)(s_src + (size_t)jn * 256) : make_uint4(0,0,0,0);

        bf16x8 kf[4][2];
        #pragma unroll
        for (int js = 0; js < 4; js++)
            #pragma unroll
            for (int ks = 0; ks < 2; ks++)
                kf[js][ks] = *(const bf16x8*)&Ks[cur][sw(js * 16 + ln, ks * 32 + g * 8, 64)];

        float csl[4] = {0.f, 0.f, 0.f, 0.f};
        #pragma unroll
        for (int t = 0; t < 3; t++) {
            if (t >= nmt) break;
            const int mt = mtsA[t];
            f32x4 acc[4] = {};
            #pragma unroll
            for (int ks = 0; ks < 2; ks++)
                #pragma unroll
                for (int js = 0; js < 4; js++)
                    acc[js] = __builtin_amdgcn_mfma_f32_16x16x32_bf16(Qf[t][ks], kf[js][ks], acc[js], 0, 0, 0);
            #pragma unroll
            for (int js = 0; js < 4; js++) {
                u16 pb[4];
                #pragma unroll
                for (int r = 0; r < 4; r++) {
                    float p = __expf(acc[js][r]);
                    csl[js] += p * rr[t][r];
                    pb[r] = f2b(p);
                }
                *(ushort4*)&U.s2.PT[sw(js * 16 + ln, mt * 16 + g * 4, 320)] = *(ushort4*)pb;
            }
        }
        #pragma unroll
        for (int js = 0; js < 4; js++) {
            float v = csl[js];
            v += __shfl_xor(v, 16);
            v += __shfl_xor(v, 32);
            csl[js] = v;
        }
        if (g == 0) {
            #pragma unroll
            for (int js = 0; js < 4; js++) colpart[w][js * 16 + ln] = csl[js];
        }
        *(uint4*)&Ks[cur ^ 1][sw(s_jj, s_ch * 8, 64)] = kv;
        __syncthreads();

        // ctx_p tile (swapped operands: thread owns row j, cols ds2*16+g*4..+3)
        {
            const int js2 = w & 3, ds2 = w >> 2;
            f32x4 ap = {};
            #pragma unroll
            for (int k = 0; k < 10; k++) {
                bf16x8 af = *(const bf16x8*)&U.s2.PT[sw(js2 * 16 + ln, k * 32 + g * 8, 320)];
                bf16x8 bv = *(const bf16x8*)&U.s2.VdT[sw(ds2 * 16 + ln, k * 32 + g * 8, 320)];
                ap = __builtin_amdgcn_mfma_f32_16x16x32_bf16(bv, af, ap, 0, 0, 0);
            }
            const int j = j0 + js2 * 16 + ln;
            if (j < PLc) {
                u16 o[4];
                #pragma unroll
                for (int r = 0; r < 4; r++) o[r] = f2b(ap[r]);
                *(uint2*)&ctx_p[rbp + (size_t)j * 256 + ds2 * 16 + g * 4] = *(uint2*)o;
            }
        }
        if (w == 0) {
            float tot = 0.f;
            #pragma unroll
            for (int ww = 0; ww < 8; ww++) tot += colpart[ww][lane];
            const int j = j0 + lane;
            if (j < PLc) cm[(size_t)(b * PLc + j) * 8 + h] = tot * (1.0f / 290.0f);
        }
        __syncthreads();
    }
}

// ---------------- final combine, 4 cols/thread ----------------
__global__ __launch_bounds__(256) void combine_kernel(
        const float* __restrict__ drug, const float* __restrict__ prot,
        const float* __restrict__ scale_d, const float* __restrict__ scale_p,
        const float* __restrict__ pe,
        const u16* __restrict__ Xd, const u16* __restrict__ Xp,
        const u16* __restrict__ gate_d, const u16* __restrict__ gate_p,
        const float* __restrict__ cm,
        const float* __restrict__ w_fc_dp, const float* __restrict__ b_fc_dp,
        const float* __restrict__ w_fc_pd, const float* __restrict__ b_fc_pd,
        float* __restrict__ out) {
    int idx = blockIdx.x * 256 + threadIdx.x;
    int r = idx >> 6, c4 = (idx & 63) * 4;
    if (r < MD) {
        int b = r / DLn, i = r % DLn;
        float s = scale_d[0];
        float4 dv = *(const float4*)&drug[(size_t)r * 256 + c4];
        float4 pv = *(const float4*)&pe[i * 256 + c4];
        uint2 xv = *(const uint2*)&Xd[(size_t)r * 256 + c4];
        uint2 gv = *(const uint2*)&gate_d[(size_t)r * 256 + c4];
        float4 bb = *(const float4*)&b_fc_dp[c4];
        float da[4] = { bb.x, bb.y, bb.z, bb.w };
        #pragma unroll
        for (int hh = 0; hh < 8; hh++) {
            float4 wv = *(const float4*)&w_fc_dp[hh * 256 + c4];
            da[0] += 0.001f * wv.x; da[1] += 0.001f * wv.y;
            da[2] += 0.001f * wv.z; da[3] += 0.001f * wv.w;
        }
        u16 xe[4]; *(uint2*)xe = xv;
        u16 ge[4]; *(uint2*)ge = gv;
        float e0 = dv.x + s * pv.x, e1 = dv.y + s * pv.y;
        float e2 = dv.z + s * pv.z, e3 = dv.w + s * pv.w;
        float4 o;
        o.x = e0 + b2f(xe[0]) * b2f(ge[0]) * sigm(da[0]);
        o.y = e1 + b2f(xe[1]) * b2f(ge[1]) * sigm(da[1]);
        o.z = e2 + b2f(xe[2]) * b2f(ge[2]) * sigm(da[2]);
        o.w = e3 + b2f(xe[3]) * b2f(ge[3]) * sigm(da[3]);
        *(float4*)&out[((size_t)b * 1290 + i) * 256 + c4] = o;
    } else {
        int rr = r - MD;
        int b = rr / PLc, j = rr % PLc;
        float s = scale_p[0];
        float4 dv = *(const float4*)&prot[(size_t)rr * 256 + c4];
        float4 pv = *(const float4*)&pe[j * 256 + c4];
        uint2 xv = *(const uint2*)&Xp[(size_t)rr * 256 + c4];
        uint2 gv = *(const uint2*)&gate_p[(size_t)rr * 256 + c4];
        float4 bb = *(const float4*)&b_fc_pd[c4];
        float pa[4] = { bb.x, bb.y, bb.z, bb.w };
        #pragma unroll
        for (int hh = 0; hh < 8; hh++) {
            float cmh = cm[(size_t)rr * 8 + hh];
            float4 wv = *(const float4*)&w_fc_pd[hh * 256 + c4];
            pa[0] += cmh * wv.x; pa[1] += cmh * wv.y;
            pa[2] += cmh * wv.z; pa[3] += cmh * wv.w;
        }
        u16 xe[4]; *(uint2*)xe = xv;
        u16 ge[4]; *(uint2*)ge = gv;
        float e0 = dv.x + s * pv.x, e1 = dv.y + s * pv.y;
        float e2 = dv.z + s * pv.z, e3 = dv.w + s * pv.w;
        float4 o;
        o.x = e0 + b2f(xe[0]) * b2f(ge[0]) * sigm(pa[0]);
        o.y = e1 + b2f(xe[1]) * b2f(ge[1]) * sigm(pa[1]);
        o.z = e2 + b2f(xe[2]) * b2f(ge[2]) * sigm(pa[2]);
        o.w = e3 + b2f(xe[3]) * b2f(ge[3]) * sigm(pa[3]);
        *(float4*)&out[((size_t)b * 1290 + 290 + j) * 256 + c4] = o;
    }
}

extern "C" void kernel_launch(void* const* d_in, const int* in_sizes, int n_in,
                              void* d_out, int out_size, void* d_ws, size_t ws_size,
                              hipStream_t stream) {
    (void)in_sizes; (void)n_in; (void)out_size;
    const float* drug    = (const float*)d_in[0];
    const float* prot    = (const float*)d_in[1];
    const float* scale_d = (const float*)d_in[2];
    const float* scale_p = (const float*)d_in[3];

    char* ws = (char*)d_ws;
    size_t off = 0;
    auto alloc = [&](size_t bytes) -> void* {
        void* p = ws + off;
        off += (bytes + 255) & ~(size_t)255;
        return p;
    };
    float* pe   = (float*)alloc((size_t)1000 * 256 * 4);
    u16* wt     = (u16*)alloc((size_t)10 * 65536 * 2);
    u16* Qd     = (u16*)alloc((size_t)MD * 256 * 2);
    u16* Kd     = (u16*)alloc((size_t)MD * 256 * 2);
    u16* Vd     = (u16*)alloc((size_t)MD * 256 * 2);
    u16* gate_d = (u16*)alloc((size_t)MD * 256 * 2);
    u16* Kp     = (u16*)alloc((size_t)MP * 256 * 2);
    u16* Vp     = (u16*)alloc((size_t)MP * 256 * 2);
    u16* Qp     = (u16*)alloc((size_t)MP * 256 * 2);
    u16* gate_p = (u16*)alloc((size_t)MP * 256 * 2);
    u16* ctxd   = (u16*)alloc((size_t)MD * 256 * 2);
    u16* ctxp   = (u16*)alloc((size_t)MP * 256 * 2);
    float* cm   = (float*)alloc((size_t)MP * 8 * 4);
    u16* Xd     = (u16*)alloc((size_t)MD * 256 * 2);
    u16* Xp     = (u16*)alloc((size_t)MP * 256 * 2);
    if (off > ws_size) return;

    pe_kernel<<<1000, 256, 0, stream>>>(pe);

    WPtrs wp;
    const int wsrc[10] = {4, 12, 14, 25, 6, 8, 10, 27, 16, 18};
    for (int m = 0; m < 10; m++) wp.w[m] = (const float*)d_in[wsrc[m]];
    wprep_kernel<<<dim3(16, 10), 256, 0, stream>>>(wp, wt);

    auto W = [&](int slot) { return wt + (size_t)slot * 65536; };

    PCfg2 p1;
    p1.split = 145;
    p1.c0 = { nullptr, drug, scale_d, pe, DLn,
              { { W(0), (const float*)d_in[5],  Qd,     0 },
                { W(1), (const float*)d_in[13], Kd,     0 },
                { W(2), (const float*)d_in[15], Vd,     0 },
                { W(3), (const float*)d_in[26], gate_d, 1 } } };
    p1.c1 = { nullptr, prot, scale_p, pe, PLc,
              { { W(4), (const float*)d_in[7],  Kp,     0 },
                { W(5), (const float*)d_in[9],  Vp,     0 },
                { W(6), (const float*)d_in[11], Qp,     0 },
                { W(7), (const float*)d_in[28], gate_p, 1 } } };
    proj_kernel<4><<<645, 256, 0, stream>>>(p1);

    attn_kernel<<<256, 512, 0, stream>>>(Qd, Kd, Vd, Kp, Vp, Qp,
                                         (const float*)d_in[20], ctxd, ctxp, cm);

    PCfg2 p2;
    p2.split = 145;
    p2.c0 = { ctxd, nullptr, nullptr, nullptr, DLn,
              { { W(8), (const float*)d_in[17], Xd, 0 }, {}, {}, {} } };
    p2.c1 = { ctxp, nullptr, nullptr, nullptr, PLc,
              { { W(9), (const float*)d_in[19], Xp, 0 }, {}, {}, {} } };
    proj_kernel<1><<<645, 256, 0, stream>>>(p2);

    combine_kernel<<<(MD + MP) / 4, 256, 0, stream>>>(drug, prot, scale_d, scale_p, pe,
        Xd, Xp, gate_d, gate_p, cm,
        (const float*)d_in[21], (const float*)d_in[22],
        (const float*)d_in[23], (const float*)d_in[24],
        (float*)d_out);
}

// Round 9
// 203.997 us; speedup vs baseline: 1.6111x; 1.2965x over previous
//
#include <hip/hip_runtime.h>
#include <math.h>

typedef __attribute__((ext_vector_type(8))) short bf16x8;
typedef __attribute__((ext_vector_type(4))) float f32x4;
typedef unsigned short u16;
typedef unsigned int u32;

#define DEVFN static __device__ __forceinline__

constexpr int NB  = 32;
constexpr int DLn = 290;
constexpr int PLc = 1000;
constexpr int MD  = NB * DLn;   // 9280  = 145*64
constexpr int MP  = NB * PLc;   // 32000 = 500*64
constexpr int NSTRIP = 645;     // 145 + 500
constexpr int SPLIT  = 145;

DEVFN u16 f2b(float f) {
    u32 u = __builtin_bit_cast(u32, f);
    u32 r = u + 0x7fffu + ((u >> 16) & 1u);
    return (u16)(r >> 16);
}
DEVFN float b2f(u16 s) { return __builtin_bit_cast(float, (u32)s << 16); }
DEVFN float sigm(float x) { return 1.0f / (1.0f + __expf(-x)); }
// XOR-swizzled LDS index (u16 units); stride multiple of 8 u16. 16B-aligned.
DEVFN int sw(int row, int col, int stride) { return row * stride + (col ^ ((row & 7) << 3)); }

// ---------------- PE table ----------------
__global__ void pe_kernel(float* __restrict__ pe) {
    int p = blockIdx.x, c = threadIdx.x;
    float div = __expf((float)(c & ~1) * (-9.210340371976184f / 256.0f));
    float ang = (float)p * div;
    pe[p * 256 + c] = (c & 1) ? cosf(ang) : sinf(ang);
}

// ---------------- weight prep: WT[n][k] bf16, LDS transpose ----------------
struct WPtrs { const float* w[10]; };
__global__ __launch_bounds__(256) void wprep_kernel(WPtrs wp, u16* __restrict__ wt) {
    __shared__ u16 t[64][66];
    int m = blockIdx.y, tile = blockIdx.x;
    int k0 = (tile >> 2) * 64, n0 = (tile & 3) * 64;
    const float* w = wp.w[m];
    int r = threadIdx.x >> 6, c = threadIdx.x & 63;
    #pragma unroll
    for (int q = 0; q < 16; q++) {
        int rr = r + q * 4;
        t[rr][c] = f2b(w[(size_t)(k0 + rr) * 256 + n0 + c]);
    }
    __syncthreads();
    #pragma unroll
    for (int q = 0; q < 16; q++) {
        int rr = r + q * 4;
        wt[((size_t)m << 16) + (size_t)(n0 + rr) * 256 + k0 + c] = t[c][rr];
    }
}

// ---------------- fused projection ----------------
// Grid: d = ((sg*4 + j) << 3) | x; strip s = sg*8 + x. The 4 j-blocks of a strip
// share (d mod 8) -> same XCD -> A strip read once per XCD L2.
// NM==4 (proj1): block = (strip, matrix j), 4 chunk-phases, dbuf LDS.
// NM==1 (proj2): block = (strip, chunk j), single phase, no mid-kernel barrier.
// B staged via global_load_lds width 16: linear LDS dest, swizzle+nu folded into
// the per-lane GLOBAL source address (rule #21). No bv registers, no ds_writes.
struct PM { const u16* BT; const float* bias; u16* C; int sig; };
struct PCfg {
    const u16* Ab;
    const float* Af32;
    const float* scale;
    const float* pe;
    int plen;
    PM m[4];
};
struct PCfg2 { PCfg c0, c1; };

DEVFN void stageB(const u16* __restrict__ BT, int c, u16* dst0, int tid) {
    const int sub = tid >> 5;          // LDS row within 8-row group
    const int c32 = tid & 31;          // 8-u16 unit within row
    #pragma unroll
    for (int k = 0; k < 8; k++) {
        const int r = k * 8 + sub;     // LDS row = B-slot
        const int nur = ((r >> 5) & 1) * 32 + ((r >> 2) & 3) * 8 + ((r >> 4) & 1) * 4 + (r & 3);
        const int kcol = ((c32 ^ (r & 7)) << 3);   // inverse-swizzled source col
        const u16* src = BT + (size_t)(c * 64 + nur) * 256 + kcol;
        u16* dst = dst0 + k * 2048 + tid * 8;      // linear: wave base + lane*16B
        __builtin_amdgcn_global_load_lds(
            (const __attribute__((address_space(1))) void*)src,
            (__attribute__((address_space(3))) void*)dst, 16, 0, 0);
    }
}

template<int NM>
__global__ __launch_bounds__(256) void proj_kernel(PCfg2 cfgs) {
    const int d = blockIdx.x;
    const int x = d & 7, q = d >> 3;
    const int j = q & 3, sg = q >> 2;
    const int s = sg * 8 + x;
    if (s >= NSTRIP) return;
    const bool f1 = s < SPLIT;
    const int mt = f1 ? s : s - SPLIT;

    const u16*   Ab    = f1 ? cfgs.c0.Ab    : cfgs.c1.Ab;
    const float* Af32  = f1 ? cfgs.c0.Af32  : cfgs.c1.Af32;
    const float* scale = f1 ? cfgs.c0.scale : cfgs.c1.scale;
    const float* pe    = f1 ? cfgs.c0.pe    : cfgs.c1.pe;
    const int    plen  = f1 ? cfgs.c0.plen  : cfgs.c1.plen;
    // matrix select: NM==4 -> j (runtime uniform), NM==1 -> 0
    const int mi = (NM == 4) ? j : 0;
    const u16*   BT   = f1 ? (mi==0?cfgs.c0.m[0].BT  :mi==1?cfgs.c0.m[1].BT  :mi==2?cfgs.c0.m[2].BT  :cfgs.c0.m[3].BT)
                           : (mi==0?cfgs.c1.m[0].BT  :mi==1?cfgs.c1.m[1].BT  :mi==2?cfgs.c1.m[2].BT  :cfgs.c1.m[3].BT);
    const float* bias = f1 ? (mi==0?cfgs.c0.m[0].bias:mi==1?cfgs.c0.m[1].bias:mi==2?cfgs.c0.m[2].bias:cfgs.c0.m[3].bias)
                           : (mi==0?cfgs.c1.m[0].bias:mi==1?cfgs.c1.m[1].bias:mi==2?cfgs.c1.m[2].bias:cfgs.c1.m[3].bias);
    u16*         C    = f1 ? (mi==0?cfgs.c0.m[0].C   :mi==1?cfgs.c0.m[1].C   :mi==2?cfgs.c0.m[2].C   :cfgs.c0.m[3].C)
                           : (mi==0?cfgs.c1.m[0].C   :mi==1?cfgs.c1.m[1].C   :mi==2?cfgs.c1.m[2].C   :cfgs.c1.m[3].C);
    const int    sig  = f1 ? (mi==0?cfgs.c0.m[0].sig :mi==1?cfgs.c0.m[1].sig :mi==2?cfgs.c0.m[2].sig :cfgs.c0.m[3].sig)
                           : (mi==0?cfgs.c1.m[0].sig :mi==1?cfgs.c1.m[1].sig :mi==2?cfgs.c1.m[2].sig :cfgs.c1.m[3].sig);

    __shared__ u16 Bs[(NM == 4) ? 2 : 1][64 * 256];
    const int tid = threadIdx.x;
    const int lane = tid & 63, w = tid >> 6, ln = lane & 15, g = lane >> 4;

    // ---- first B stage issued BEFORE A-frag build (overlap) ----
    stageB(BT, (NM == 4) ? 0 : j, &Bs[0][0], tid);

    // ---- A fragments in registers: row mt*64 + w*16 + ln, k = ks*32 + g*8 ----
    bf16x8 Af[8];
    {
        const int row = mt * 64 + w * 16 + ln;
        if (Af32) {
            const int i = row % plen;
            const float sc = scale[0];
            const float* Xp_ = Af32 + (size_t)row * 256 + g * 8;
            const float* Pe_ = pe + (size_t)i * 256 + g * 8;
            #pragma unroll
            for (int ks = 0; ks < 8; ks++) {
                float4 xa = *(const float4*)(Xp_ + ks * 32);
                float4 xb = *(const float4*)(Xp_ + ks * 32 + 4);
                float4 pa = *(const float4*)(Pe_ + ks * 32);
                float4 pb = *(const float4*)(Pe_ + ks * 32 + 4);
                u16 o[8];
                o[0] = f2b(xa.x + sc * pa.x); o[1] = f2b(xa.y + sc * pa.y);
                o[2] = f2b(xa.z + sc * pa.z); o[3] = f2b(xa.w + sc * pa.w);
                o[4] = f2b(xb.x + sc * pb.x); o[5] = f2b(xb.y + sc * pb.y);
                o[6] = f2b(xb.z + sc * pb.z); o[7] = f2b(xb.w + sc * pb.w);
                Af[ks] = *(bf16x8*)o;
            }
        } else {
            const u16* Ap = Ab + (size_t)row * 256 + g * 8;
            #pragma unroll
            for (int ks = 0; ks < 8; ks++)
                Af[ks] = *(const bf16x8*)(Ap + ks * 32);
        }
    }
    asm volatile("s_waitcnt vmcnt(0)" ::: "memory");
    __syncthreads();

    #pragma unroll
    for (int c = 0; c < ((NM == 4) ? 4 : 1); c++) {
        const int cur = (NM == 4) ? (c & 1) : 0;
        const int chunk = (NM == 4) ? c : j;
        if (NM == 4 && c < 3) stageB(BT, c + 1, &Bs[(c + 1) & 1][0], tid);
        // compute: D = Bfrag * Afrag  (C^T fragment)
        f32x4 acc[4] = {};
        #pragma unroll
        for (int ks = 0; ks < 8; ks++) {
            #pragma unroll
            for (int nt = 0; nt < 4; nt++) {
                bf16x8 bf = *(const bf16x8*)&Bs[cur][sw(nt * 16 + ln, ks * 32 + g * 8, 256)];
                acc[nt] = __builtin_amdgcn_mfma_f32_16x16x32_bf16(bf, Af[ks], acc[nt], 0, 0, 0);
            }
        }
        // epilogue: thread owns row mt*64+w*16+ln, 16 consecutive cols (2 x 16B)
        {
            const int row = mt * 64 + w * 16 + ln;
            const int base0 = chunk * 64 + g * 8, base1 = base0 + 32;
            f32x4 b0 = *(const f32x4*)&bias[base0];
            f32x4 b1 = *(const f32x4*)&bias[base0 + 4];
            f32x4 b2 = *(const f32x4*)&bias[base1];
            f32x4 b3 = *(const f32x4*)&bias[base1 + 4];
            float v[16];
            #pragma unroll
            for (int t = 0; t < 4; t++) {
                v[t]      = acc[0][t] + b0[t];
                v[4 + t]  = acc[1][t] + b1[t];
                v[8 + t]  = acc[2][t] + b2[t];
                v[12 + t] = acc[3][t] + b3[t];
            }
            if (sig) {
                #pragma unroll
                for (int t = 0; t < 16; t++) v[t] = sigm(v[t]);
            }
            u16 o[16];
            #pragma unroll
            for (int t = 0; t < 16; t++) o[t] = f2b(v[t]);
            u16* Cp = C + (size_t)row * 256;
            *(uint4*)&Cp[base0] = *(uint4*)&o[0];
            *(uint4*)&Cp[base1] = *(uint4*)&o[8];
        }
        if (NM == 4 && c < 3) {
            asm volatile("s_waitcnt vmcnt(0)" ::: "memory");
            __syncthreads();
        }
    }
}

// ---------------- attention: one block per (b,h), no-max softmax, 2 sweeps ----------------
__global__ __launch_bounds__(512) void attn_kernel(
        const u16* __restrict__ Qd, const u16* __restrict__ Kd, const u16* __restrict__ Vd,
        const u16* __restrict__ Kp, const u16* __restrict__ Vp, const u16* __restrict__ Qp,
        const float* __restrict__ alpha,
        u16* __restrict__ ctx_d, u16* __restrict__ ctx_p, float* __restrict__ cm) {
    __shared__ u16 Ks[2][64 * 64];
    __shared__ union {
        struct { u16 VpT[2][32 * 64]; u16 Pm[320 * 64]; } s1;
        struct { u16 PT[64 * 320]; u16 VdT[32 * 320]; } s2;
    } U;
    __shared__ float r_l[320];
    __shared__ float colpart[8][64];

    const int bh = blockIdx.x, b = bh >> 3, h = bh & 7;
    const int tid = threadIdx.x;
    const int w = tid >> 6, lane = tid & 63, ln = lane & 15, g = lane >> 4;

    const float a = sigm(alpha[0]);
    const float inv = 0.1767766952966369f;
    const float sa = a * inv, sb = (1.0f - a) * inv;
    const int nmt = (w < 4) ? 3 : 2;
    const int mtsA[3] = { w, w + 8, w + 16 };

    const size_t rbd = (size_t)b * DLn * 256 + h * 32;
    const size_t rbp = (size_t)b * PLc * 256 + h * 32;

    bf16x8 Qf[3][2];
    #pragma unroll
    for (int t = 0; t < 3; t++) {
        const int i = mtsA[t] * 16 + ln;
        #pragma unroll
        for (int ks = 0; ks < 2; ks++) {
            u16 o[8] = {0,0,0,0,0,0,0,0};
            if (t < nmt && i < DLn) {
                const u16* src = (ks ? Kd : Qd) + rbd + (size_t)i * 256 + g * 8;
                const float s = ks ? sb : sa;
                uint4 v = *(const uint4*)src;
                u16 e[8]; *(uint4*)e = v;
                #pragma unroll
                for (int q = 0; q < 8; q++) o[q] = f2b(b2f(e[q]) * s);
            }
            Qf[t][ks] = *(bf16x8*)o;
        }
    }

    const int s_jj = tid >> 3, s_ch = tid & 7;
    const u16* s_src = ((s_ch >> 2) ? Qp : Kp) + rbp + (s_ch & 3) * 8;
    const int v_j = tid & 63, v_d0 = (tid >> 6) * 4;

    {
        int j = s_jj;
        uint4 kv = (j < PLc) ? *(const uint4*)(s_src + (size_t)j * 256) : make_uint4(0,0,0,0);
        uint2 vv = (v_j < PLc) ? *(const uint2*)(Vp + rbp + (size_t)v_j * 256 + v_d0) : make_uint2(0,0);
        *(uint4*)&Ks[0][sw(s_jj, s_ch * 8, 64)] = kv;
        u16 e[4]; *(uint2*)e = vv;
        #pragma unroll
        for (int q = 0; q < 4; q++) U.s1.VpT[0][sw(v_d0 + q, v_j, 64)] = e[q];
    }
    __syncthreads();

    float rs[3] = {0.f, 0.f, 0.f};
    f32x4 accd[3][2] = {};
    for (int jt = 0; jt < 16; jt++) {
        const int cur = jt & 1, j0 = jt * 64;
        const int jn = j0 + 64 + s_jj;
        uint4 kv = (jn < PLc) ? *(const uint4*)(s_src + (size_t)jn * 256) : make_uint4(0,0,0,0);
        const int vn = j0 + 64 + v_j;
        uint2 vv = (vn < PLc) ? *(const uint2*)(Vp + rbp + (size_t)vn * 256 + v_d0) : make_uint2(0,0);

        bf16x8 kf[4][2];
        #pragma unroll
        for (int js = 0; js < 4; js++)
            #pragma unroll
            for (int ks = 0; ks < 2; ks++)
                kf[js][ks] = *(const bf16x8*)&Ks[cur][sw(js * 16 + ln, ks * 32 + g * 8, 64)];

        #pragma unroll
        for (int t = 0; t < 3; t++) {
            if (t >= nmt) break;
            const int mt = mtsA[t];
            f32x4 acc[4] = {};
            #pragma unroll
            for (int ks = 0; ks < 2; ks++)
                #pragma unroll
                for (int js = 0; js < 4; js++)
                    acc[js] = __builtin_amdgcn_mfma_f32_16x16x32_bf16(kf[js][ks], Qf[t][ks], acc[js], 0, 0, 0);
            const int irow = mt * 16 + ln;
            #pragma unroll
            for (int js = 0; js < 4; js++) {
                u16 pb[4];
                float psum = 0.f;
                #pragma unroll
                for (int r = 0; r < 4; r++) {
                    float p = __expf(acc[js][r]);
                    psum += p;
                    pb[r] = f2b(p);
                }
                rs[t] += psum;
                *(ushort4*)&U.s1.Pm[sw(irow, js * 16 + g * 4, 64)] = *(ushort4*)pb;
            }
        }
        // ctx_d accumulate (swapped operands: D row -> d, col -> i)
        #pragma unroll
        for (int t = 0; t < 3; t++) {
            if (t >= nmt) break;
            const int mt = mtsA[t];
            #pragma unroll
            for (int ks2 = 0; ks2 < 2; ks2++) {
                bf16x8 af = *(const bf16x8*)&U.s1.Pm[sw(mt * 16 + ln, ks2 * 32 + g * 8, 64)];
                #pragma unroll
                for (int nd = 0; nd < 2; nd++) {
                    bf16x8 bv = *(const bf16x8*)&U.s1.VpT[cur][sw(nd * 16 + ln, ks2 * 32 + g * 8, 64)];
                    accd[t][nd] = __builtin_amdgcn_mfma_f32_16x16x32_bf16(bv, af, accd[t][nd], 0, 0, 0);
                }
            }
        }
        *(uint4*)&Ks[cur ^ 1][sw(s_jj, s_ch * 8, 64)] = kv;
        {
            u16 e[4]; *(uint2*)e = vv;
            #pragma unroll
            for (int q = 0; q < 4; q++) U.s1.VpT[cur ^ 1][sw(v_d0 + q, v_j, 64)] = e[q];
        }
        __syncthreads();
    }

    #pragma unroll
    for (int t = 0; t < 3; t++) {
        float v = rs[t];
        v += __shfl_xor(v, 16);
        v += __shfl_xor(v, 32);
        rs[t] = v;
    }
    if (g == 0) {
        #pragma unroll
        for (int t = 0; t < 3; t++) {
            if (t >= nmt) break;
            const int i = mtsA[t] * 16 + ln;
            r_l[i] = (i < DLn) ? 1.0f / (rs[t] - 24.0f) : 0.0f;
        }
    }
    __syncthreads();

    // ---- ctx_d write: thread owns row i = mt*16+ln, cols nd*16 + g*4 .. +3 ----
    #pragma unroll
    for (int t = 0; t < 3; t++) {
        if (t >= nmt) break;
        const int i = mtsA[t] * 16 + ln;
        if (i < DLn) {
            const float ri = r_l[i];
            #pragma unroll
            for (int nd = 0; nd < 2; nd++) {
                u16 o[4];
                #pragma unroll
                for (int r = 0; r < 4; r++) o[r] = f2b(accd[t][nd][r] * ri);
                *(uint2*)&ctx_d[rbd + (size_t)i * 256 + nd * 16 + g * 4] = *(uint2*)o;
            }
        }
    }
    for (int c = tid; c < 320 * 8; c += 512) {
        const int i = c >> 3, d0 = (c & 7) * 4;
        u16 o[4] = {0,0,0,0};
        if (i < DLn) {
            const float ri = r_l[i];
            uint2 v = *(const uint2*)(Vd + rbd + (size_t)i * 256 + d0);
            u16 e[4]; *(uint2*)e = v;
            #pragma unroll
            for (int q = 0; q < 4; q++) o[q] = f2b(b2f(e[q]) * ri);
        }
        #pragma unroll
        for (int q = 0; q < 4; q++) U.s2.VdT[sw(d0 + q, i, 320)] = o[q];
    }
    {
        int j = s_jj;
        uint4 kv = (j < PLc) ? *(const uint4*)(s_src + (size_t)j * 256) : make_uint4(0,0,0,0);
        *(uint4*)&Ks[0][sw(s_jj, s_ch * 8, 64)] = kv;
    }
    float rr[3][4];
    #pragma unroll
    for (int t = 0; t < 3; t++)
        #pragma unroll
        for (int r = 0; r < 4; r++)
            rr[t][r] = (t < nmt) ? r_l[mtsA[t] * 16 + g * 4 + r] : 0.0f;
    __syncthreads();

    for (int jt = 0; jt < 16; jt++) {
        const int cur = jt & 1, j0 = jt * 64;
        const int jn = j0 + 64 + s_jj;
        uint4 kv = (jn < PLc) ? *(const uint4*)(s_src + (size_t)jn * 256) : make_uint4(0,0,0,0);

        bf16x8 kf[4][2];
        #pragma unroll
        for (int js = 0; js < 4; js++)
            #pragma unroll
            for (int ks = 0; ks < 2; ks++)
                kf[js][ks] = *(const bf16x8*)&Ks[cur][sw(js * 16 + ln, ks * 32 + g * 8, 64)];

        float csl[4] = {0.f, 0.f, 0.f, 0.f};
        #pragma unroll
        for (int t = 0; t < 3; t++) {
            if (t >= nmt) break;
            const int mt = mtsA[t];
            f32x4 acc[4] = {};
            #pragma unroll
            for (int ks = 0; ks < 2; ks++)
                #pragma unroll
                for (int js = 0; js < 4; js++)
                    acc[js] = __builtin_amdgcn_mfma_f32_16x16x32_bf16(Qf[t][ks], kf[js][ks], acc[js], 0, 0, 0);
            #pragma unroll
            for (int js = 0; js < 4; js++) {
                u16 pb[4];
                #pragma unroll
                for (int r = 0; r < 4; r++) {
                    float p = __expf(acc[js][r]);
                    csl[js] += p * rr[t][r];
                    pb[r] = f2b(p);
                }
                *(ushort4*)&U.s2.PT[sw(js * 16 + ln, mt * 16 + g * 4, 320)] = *(ushort4*)pb;
            }
        }
        #pragma unroll
        for (int js = 0; js < 4; js++) {
            float v = csl[js];
            v += __shfl_xor(v, 16);
            v += __shfl_xor(v, 32);
            csl[js] = v;
        }
        if (g == 0) {
            #pragma unroll
            for (int js = 0; js < 4; js++) colpart[w][js * 16 + ln] = csl[js];
        }
        *(uint4*)&Ks[cur ^ 1][sw(s_jj, s_ch * 8, 64)] = kv;
        __syncthreads();

        // ctx_p tile (swapped operands: thread owns row j, cols ds2*16+g*4..+3)
        {
            const int js2 = w & 3, ds2 = w >> 2;
            f32x4 ap = {};
            #pragma unroll
            for (int k = 0; k < 10; k++) {
                bf16x8 af = *(const bf16x8*)&U.s2.PT[sw(js2 * 16 + ln, k * 32 + g * 8, 320)];
                bf16x8 bv = *(const bf16x8*)&U.s2.VdT[sw(ds2 * 16 + ln, k * 32 + g * 8, 320)];
                ap = __builtin_amdgcn_mfma_f32_16x16x32_bf16(bv, af, ap, 0, 0, 0);
            }
            const int j = j0 + js2 * 16 + ln;
            if (j < PLc) {
                u16 o[4];
                #pragma unroll
                for (int r = 0; r < 4; r++) o[r] = f2b(ap[r]);
                *(uint2*)&ctx_p[rbp + (size_t)j * 256 + ds2 * 16 + g * 4] = *(uint2*)o;
            }
        }
        if (w == 0) {
            float tot = 0.f;
            #pragma unroll
            for (int ww = 0; ww < 8; ww++) tot += colpart[ww][lane];
            const int j = j0 + lane;
            if (j < PLc) cm[(size_t)(b * PLc + j) * 8 + h] = tot * (1.0f / 290.0f);
        }
        __syncthreads();
    }
}

// ---------------- final combine, 4 cols/thread ----------------
__global__ __launch_bounds__(256) void combine_kernel(
        const float* __restrict__ drug, const float* __restrict__ prot,
        const float* __restrict__ scale_d, const float* __restrict__ scale_p,
        const float* __restrict__ pe,
        const u16* __restrict__ Xd, const u16* __restrict__ Xp,
        const u16* __restrict__ gate_d, const u16* __restrict__ gate_p,
        const float* __restrict__ cm,
        const float* __restrict__ w_fc_dp, const float* __restrict__ b_fc_dp,
        const float* __restrict__ w_fc_pd, const float* __restrict__ b_fc_pd,
        float* __restrict__ out) {
    int idx = blockIdx.x * 256 + threadIdx.x;
    int r = idx >> 6, c4 = (idx & 63) * 4;
    if (r < MD) {
        int b = r / DLn, i = r % DLn;
        float s = scale_d[0];
        float4 dv = *(const float4*)&drug[(size_t)r * 256 + c4];
        float4 pv = *(const float4*)&pe[i * 256 + c4];
        uint2 xv = *(const uint2*)&Xd[(size_t)r * 256 + c4];
        uint2 gv = *(const uint2*)&gate_d[(size_t)r * 256 + c4];
        float4 bb = *(const float4*)&b_fc_dp[c4];
        float da[4] = { bb.x, bb.y, bb.z, bb.w };
        #pragma unroll
        for (int hh = 0; hh < 8; hh++) {
            float4 wv = *(const float4*)&w_fc_dp[hh * 256 + c4];
            da[0] += 0.001f * wv.x; da[1] += 0.001f * wv.y;
            da[2] += 0.001f * wv.z; da[3] += 0.001f * wv.w;
        }
        u16 xe[4]; *(uint2*)xe = xv;
        u16 ge[4]; *(uint2*)ge = gv;
        float e0 = dv.x + s * pv.x, e1 = dv.y + s * pv.y;
        float e2 = dv.z + s * pv.z, e3 = dv.w + s * pv.w;
        float4 o;
        o.x = e0 + b2f(xe[0]) * b2f(ge[0]) * sigm(da[0]);
        o.y = e1 + b2f(xe[1]) * b2f(ge[1]) * sigm(da[1]);
        o.z = e2 + b2f(xe[2]) * b2f(ge[2]) * sigm(da[2]);
        o.w = e3 + b2f(xe[3]) * b2f(ge[3]) * sigm(da[3]);
        *(float4*)&out[((size_t)b * 1290 + i) * 256 + c4] = o;
    } else {
        int rr = r - MD;
        int b = rr / PLc, j = rr % PLc;
        float s = scale_p[0];
        float4 dv = *(const float4*)&prot[(size_t)rr * 256 + c4];
        float4 pv = *(const float4*)&pe[j * 256 + c4];
        uint2 xv = *(const uint2*)&Xp[(size_t)rr * 256 + c4];
        uint2 gv = *(const uint2*)&gate_p[(size_t)rr * 256 + c4];
        float4 bb = *(const float4*)&b_fc_pd[c4];
        float pa[4] = { bb.x, bb.y, bb.z, bb.w };
        #pragma unroll
        for (int hh = 0; hh < 8; hh++) {
            float cmh = cm[(size_t)rr * 8 + hh];
            float4 wv = *(const float4*)&w_fc_pd[hh * 256 + c4];
            pa[0] += cmh * wv.x; pa[1] += cmh * wv.y;
            pa[2] += cmh * wv.z; pa[3] += cmh * wv.w;
        }
        u16 xe[4]; *(uint2*)xe = xv;
        u16 ge[4]; *(uint2*)ge = gv;
        float e0 = dv.x + s * pv.x, e1 = dv.y + s * pv.y;
        float e2 = dv.z + s * pv.z, e3 = dv.w + s * pv.w;
        float4 o;
        o.x = e0 + b2f(xe[0]) * b2f(ge[0]) * sigm(pa[0]);
        o.y = e1 + b2f(xe[1]) * b2f(ge[1]) * sigm(pa[1]);
        o.z = e2 + b2f(xe[2]) * b2f(ge[2]) * sigm(pa[2]);
        o.w = e3 + b2f(xe[3]) * b2f(ge[3]) * sigm(pa[3]);
        *(float4*)&out[((size_t)b * 1290 + 290 + j) * 256 + c4] = o;
    }
}

extern "C" void kernel_launch(void* const* d_in, const int* in_sizes, int n_in,
                              void* d_out, int out_size, void* d_ws, size_t ws_size,
                              hipStream_t stream) {
    (void)in_sizes; (void)n_in; (void)out_size;
    const float* drug    = (const float*)d_in[0];
    const float* prot    = (const float*)d_in[1];
    const float* scale_d = (const float*)d_in[2];
    const float* scale_p = (const float*)d_in[3];

    char* ws = (char*)d_ws;
    size_t off = 0;
    auto alloc = [&](size_t bytes) -> void* {
        void* p = ws + off;
        off += (bytes + 255) & ~(size_t)255;
        return p;
    };
    float* pe   = (float*)alloc((size_t)1000 * 256 * 4);
    u16* wt     = (u16*)alloc((size_t)10 * 65536 * 2);
    u16* Qd     = (u16*)alloc((size_t)MD * 256 * 2);
    u16* Kd     = (u16*)alloc((size_t)MD * 256 * 2);
    u16* Vd     = (u16*)alloc((size_t)MD * 256 * 2);
    u16* gate_d = (u16*)alloc((size_t)MD * 256 * 2);
    u16* Kp     = (u16*)alloc((size_t)MP * 256 * 2);
    u16* Vp     = (u16*)alloc((size_t)MP * 256 * 2);
    u16* Qp     = (u16*)alloc((size_t)MP * 256 * 2);
    u16* gate_p = (u16*)alloc((size_t)MP * 256 * 2);
    u16* ctxd   = (u16*)alloc((size_t)MD * 256 * 2);
    u16* ctxp   = (u16*)alloc((size_t)MP * 256 * 2);
    float* cm   = (float*)alloc((size_t)MP * 8 * 4);
    u16* Xd     = (u16*)alloc((size_t)MD * 256 * 2);
    u16* Xp     = (u16*)alloc((size_t)MP * 256 * 2);
    if (off > ws_size) return;

    pe_kernel<<<1000, 256, 0, stream>>>(pe);

    WPtrs wp;
    const int wsrc[10] = {4, 12, 14, 25, 6, 8, 10, 27, 16, 18};
    for (int m = 0; m < 10; m++) wp.w[m] = (const float*)d_in[wsrc[m]];
    wprep_kernel<<<dim3(16, 10), 256, 0, stream>>>(wp, wt);

    auto W = [&](int slot) { return wt + (size_t)slot * 65536; };
    const int GRID = ((NSTRIP + 7) / 8) * 8 * 4;   // 2592, XCD-colocated decode

    PCfg2 p1;
    p1.c0 = { nullptr, drug, scale_d, pe, DLn,
              { { W(0), (const float*)d_in[5],  Qd,     0 },
                { W(1), (const float*)d_in[13], Kd,     0 },
                { W(2), (const float*)d_in[15], Vd,     0 },
                { W(3), (const float*)d_in[26], gate_d, 1 } } };
    p1.c1 = { nullptr, prot, scale_p, pe, PLc,
              { { W(4), (const float*)d_in[7],  Kp,     0 },
                { W(5), (const float*)d_in[9],  Vp,     0 },
                { W(6), (const float*)d_in[11], Qp,     0 },
                { W(7), (const float*)d_in[28], gate_p, 1 } } };
    proj_kernel<4><<<GRID, 256, 0, stream>>>(p1);

    attn_kernel<<<256, 512, 0, stream>>>(Qd, Kd, Vd, Kp, Vp, Qp,
                                         (const float*)d_in[20], ctxd, ctxp, cm);

    PCfg2 p2;
    p2.c0 = { ctxd, nullptr, nullptr, nullptr, DLn,
              { { W(8), (const float*)d_in[17], Xd, 0 }, {}, {}, {} } };
    p2.c1 = { ctxp, nullptr, nullptr, nullptr, PLc,
              { { W(9), (const float*)d_in[19], Xp, 0 }, {}, {}, {} } };
    proj_kernel<1><<<GRID, 256, 0, stream>>>(p2);

    combine_kernel<<<(MD + MP) / 4, 256, 0, stream>>>(drug, prot, scale_d, scale_p, pe,
        Xd, Xp, gate_d, gate_p, cm,
        (const float*)d_in[21], (const float*)d_in[22],
        (const float*)d_in[23], (const float*)d_in[24],
        (float*)d_out);
}

// Round 10
// 195.390 us; speedup vs baseline: 1.6821x; 1.0441x over previous
//
#include <hip/hip_runtime.h>
#include <math.h>

typedef __attribute__((ext_vector_type(8))) short bf16x8;
typedef __attribute__((ext_vector_type(4))) float f32x4;
typedef unsigned short u16;
typedef unsigned int u32;

#define DEVFN static __device__ __forceinline__

constexpr int NB  = 32;
constexpr int DLn = 290;
constexpr int PLc = 1000;
constexpr int MD  = NB * DLn;   // 9280  = 145*64
constexpr int MP  = NB * PLc;   // 32000 = 500*64
constexpr int NSTRIP = 645;     // 145 + 500
constexpr int SPLIT  = 145;

DEVFN u16 f2b(float f) {
    u32 u = __builtin_bit_cast(u32, f);
    u32 r = u + 0x7fffu + ((u >> 16) & 1u);
    return (u16)(r >> 16);
}
DEVFN float b2f(u16 s) { return __builtin_bit_cast(float, (u32)s << 16); }
DEVFN float sigm(float x) { return 1.0f / (1.0f + __expf(-x)); }
// XOR-swizzled LDS index (u16 units); stride multiple of 8 u16. 16B-aligned.
DEVFN int sw(int row, int col, int stride) { return row * stride + (col ^ ((row & 7) << 3)); }

// ---------------- PE table ----------------
__global__ void pe_kernel(float* __restrict__ pe) {
    int p = blockIdx.x, c = threadIdx.x;
    float div = __expf((float)(c & ~1) * (-9.210340371976184f / 256.0f));
    float ang = (float)p * div;
    pe[p * 256 + c] = (c & 1) ? cosf(ang) : sinf(ang);
}

// ---------------- weight prep: WT[n][k] bf16, LDS transpose ----------------
struct WPtrs { const float* w[10]; };
__global__ __launch_bounds__(256) void wprep_kernel(WPtrs wp, u16* __restrict__ wt) {
    __shared__ u16 t[64][66];
    int m = blockIdx.y, tile = blockIdx.x;
    int k0 = (tile >> 2) * 64, n0 = (tile & 3) * 64;
    const float* w = wp.w[m];
    int r = threadIdx.x >> 6, c = threadIdx.x & 63;
    #pragma unroll
    for (int q = 0; q < 16; q++) {
        int rr = r + q * 4;
        t[rr][c] = f2b(w[(size_t)(k0 + rr) * 256 + n0 + c]);
    }
    __syncthreads();
    #pragma unroll
    for (int q = 0; q < 16; q++) {
        int rr = r + q * 4;
        wt[((size_t)m << 16) + (size_t)(n0 + rr) * 256 + k0 + c] = t[c][rr];
    }
}

// ---------------- fused projection ----------------
// Grid: d = ((sg*4 + j) << 3) | x; strip s = sg*8 + x -> the 4 j-blocks of a
// strip share d%8 -> same XCD L2 for the A strip.
// NM==4 (proj1): block = (strip, matrix j); 4 chunk-phases, SINGLE 32KB buffer
//   (5 blocks/CU -> TLP hides stage latency).
// NM==1 (proj2): block = (strip, chunk j); 1 phase; epilogue FUSES the final
//   combine (residual + gate + attn-sigmoid) and writes fp32 out directly.
struct PM { const u16* BT; const float* bias; u16* C; int sig; };
struct PCfg {
    const u16* Ab;
    const float* Af32;
    const float* scale;
    const float* pe;
    int plen;
    PM m[4];
};
struct PCfg2 {
    PCfg c0, c1;
    // fused-combine extras (NM==1)
    const float* x0; const float* x1;       // drug, prot fp32
    const u16* gate0; const u16* gate1;
    const float* cm;                         // [MP][8]
    const float* wfc0; const float* bfc0;    // drug fc (w_fc_dp, b_fc_dp)
    const float* wfc1; const float* bfc1;    // prot fc
    float* out;
};

DEVFN void stageB(const u16* __restrict__ BT, int c, u16* dst0, int tid) {
    const int sub = tid >> 5;          // LDS row within 8-row group
    const int c32 = tid & 31;          // 8-u16 unit within row
    #pragma unroll
    for (int k = 0; k < 8; k++) {
        const int r = k * 8 + sub;     // LDS row = B-slot
        const int nur = ((r >> 5) & 1) * 32 + ((r >> 2) & 3) * 8 + ((r >> 4) & 1) * 4 + (r & 3);
        const int kcol = ((c32 ^ (r & 7)) << 3);   // inverse-swizzled source col
        const u16* src = BT + (size_t)(c * 64 + nur) * 256 + kcol;
        u16* dst = dst0 + k * 2048 + tid * 8;      // linear: wave base + lane*16B
        __builtin_amdgcn_global_load_lds(
            (const __attribute__((address_space(1))) void*)src,
            (__attribute__((address_space(3))) void*)dst, 16, 0, 0);
    }
}

template<int NM>
__global__ __launch_bounds__(256, 4) void proj_kernel(PCfg2 cfgs) {
    const int d = blockIdx.x;
    const int x = d & 7, q = d >> 3;
    const int j = q & 3, sg = q >> 2;
    const int s = sg * 8 + x;
    if (s >= NSTRIP) return;
    const bool f1 = s < SPLIT;
    const int mt = f1 ? s : s - SPLIT;

    const u16*   Ab    = f1 ? cfgs.c0.Ab    : cfgs.c1.Ab;
    const float* Af32  = f1 ? cfgs.c0.Af32  : cfgs.c1.Af32;
    const float* scale = f1 ? cfgs.c0.scale : cfgs.c1.scale;
    const float* pe    = f1 ? cfgs.c0.pe    : cfgs.c1.pe;
    const int mi = (NM == 4) ? j : 0;
    const u16*   BT   = f1 ? (mi==0?cfgs.c0.m[0].BT  :mi==1?cfgs.c0.m[1].BT  :mi==2?cfgs.c0.m[2].BT  :cfgs.c0.m[3].BT)
                           : (mi==0?cfgs.c1.m[0].BT  :mi==1?cfgs.c1.m[1].BT  :mi==2?cfgs.c1.m[2].BT  :cfgs.c1.m[3].BT);
    const float* bias = f1 ? (mi==0?cfgs.c0.m[0].bias:mi==1?cfgs.c0.m[1].bias:mi==2?cfgs.c0.m[2].bias:cfgs.c0.m[3].bias)
                           : (mi==0?cfgs.c1.m[0].bias:mi==1?cfgs.c1.m[1].bias:mi==2?cfgs.c1.m[2].bias:cfgs.c1.m[3].bias);
    u16*         C    = f1 ? (mi==0?cfgs.c0.m[0].C   :mi==1?cfgs.c0.m[1].C   :mi==2?cfgs.c0.m[2].C   :cfgs.c0.m[3].C)
                           : (mi==0?cfgs.c1.m[0].C   :mi==1?cfgs.c1.m[1].C   :mi==2?cfgs.c1.m[2].C   :cfgs.c1.m[3].C);
    const int    sig  = f1 ? (mi==0?cfgs.c0.m[0].sig :mi==1?cfgs.c0.m[1].sig :mi==2?cfgs.c0.m[2].sig :cfgs.c0.m[3].sig)
                           : (mi==0?cfgs.c1.m[0].sig :mi==1?cfgs.c1.m[1].sig :mi==2?cfgs.c1.m[2].sig :cfgs.c1.m[3].sig);

    __shared__ u16 Bs[64 * 256];   // single 32KB buffer -> 5 blocks/CU
    const int tid = threadIdx.x;
    const int lane = tid & 63, w = tid >> 6, ln = lane & 15, g = lane >> 4;

    // ---- first B stage issued BEFORE A-frag build (overlap) ----
    stageB(BT, (NM == 4) ? 0 : j, &Bs[0], tid);

    // ---- A fragments in registers: row mt*64 + w*16 + ln, k = ks*32 + g*8 ----
    const int row = mt * 64 + w * 16 + ln;
    bf16x8 Af[8];
    {
        if (Af32) {
            const int i = f1 ? (row % DLn) : (row % PLc);
            const float sc = scale[0];
            const float* Xp_ = Af32 + (size_t)row * 256 + g * 8;
            const float* Pe_ = pe + (size_t)i * 256 + g * 8;
            #pragma unroll
            for (int ks = 0; ks < 8; ks++) {
                float4 xa = *(const float4*)(Xp_ + ks * 32);
                float4 xb = *(const float4*)(Xp_ + ks * 32 + 4);
                float4 pa = *(const float4*)(Pe_ + ks * 32);
                float4 pb = *(const float4*)(Pe_ + ks * 32 + 4);
                u16 o[8];
                o[0] = f2b(xa.x + sc * pa.x); o[1] = f2b(xa.y + sc * pa.y);
                o[2] = f2b(xa.z + sc * pa.z); o[3] = f2b(xa.w + sc * pa.w);
                o[4] = f2b(xb.x + sc * pb.x); o[5] = f2b(xb.y + sc * pb.y);
                o[6] = f2b(xb.z + sc * pb.z); o[7] = f2b(xb.w + sc * pb.w);
                Af[ks] = *(bf16x8*)o;
            }
        } else {
            const u16* Ap = Ab + (size_t)row * 256 + g * 8;
            #pragma unroll
            for (int ks = 0; ks < 8; ks++)
                Af[ks] = *(const bf16x8*)(Ap + ks * 32);
        }
    }
    asm volatile("s_waitcnt vmcnt(0)" ::: "memory");
    __syncthreads();

    #pragma unroll
    for (int c = 0; c < ((NM == 4) ? 4 : 1); c++) {
        const int chunk = (NM == 4) ? c : j;
        // compute: D = Bfrag * Afrag  (C^T fragment)
        f32x4 acc[4] = {};
        #pragma unroll
        for (int ks = 0; ks < 8; ks++) {
            #pragma unroll
            for (int nt = 0; nt < 4; nt++) {
                bf16x8 bf = *(const bf16x8*)&Bs[sw(nt * 16 + ln, ks * 32 + g * 8, 256)];
                acc[nt] = __builtin_amdgcn_mfma_f32_16x16x32_bf16(bf, Af[ks], acc[nt], 0, 0, 0);
            }
        }
        const bool hasNext = (NM == 4) && (c < 3);
        if (hasNext) {
            __syncthreads();                 // all waves done reading Bs
            stageB(BT, c + 1, &Bs[0], tid);  // overwrite; epilogue overlaps flight
        }
        const int base0 = chunk * 64 + g * 8, base1 = base0 + 32;
        f32x4 b0 = *(const f32x4*)&bias[base0];
        f32x4 b1 = *(const f32x4*)&bias[base0 + 4];
        f32x4 b2 = *(const f32x4*)&bias[base1];
        f32x4 b3 = *(const f32x4*)&bias[base1 + 4];
        float v[16];
        #pragma unroll
        for (int t = 0; t < 4; t++) {
            v[t]      = acc[0][t] + b0[t];
            v[4 + t]  = acc[1][t] + b1[t];
            v[8 + t]  = acc[2][t] + b2[t];
            v[12 + t] = acc[3][t] + b3[t];
        }
        if (NM == 4) {
            // plain epilogue: bf16 store, 16 consecutive cols
            if (sig) {
                #pragma unroll
                for (int t = 0; t < 16; t++) v[t] = sigm(v[t]);
            }
            u16 o[16];
            #pragma unroll
            for (int t = 0; t < 16; t++) o[t] = f2b(v[t]);
            u16* Cp = C + (size_t)row * 256;
            *(uint4*)&Cp[base0] = *(uint4*)&o[0];
            *(uint4*)&Cp[base1] = *(uint4*)&o[8];
        } else {
            // fused combine: out = e + v*gate*sigm(attn), fp32
            (void)C; (void)sig;
            const float* X   = f1 ? cfgs.x0 : cfgs.x1;
            const u16* gate  = f1 ? cfgs.gate0 : cfgs.gate1;
            const float* wfc = f1 ? cfgs.wfc0 : cfgs.wfc1;
            const float* bfc = f1 ? cfgs.bfc0 : cfgs.bfc1;
            const float sc   = scale[0];
            const int pos  = f1 ? (row % DLn) : (row % PLc);
            const int bidx = f1 ? (row / DLn) : (row / PLc);
            const int orow = f1 ? (bidx * 1290 + pos) : (bidx * 1290 + 290 + pos);
            float cmv[8];
            if (!f1) {
                float4 ca = *(const float4*)&cfgs.cm[(size_t)row * 8];
                float4 cb = *(const float4*)&cfgs.cm[(size_t)row * 8 + 4];
                cmv[0]=ca.x; cmv[1]=ca.y; cmv[2]=ca.z; cmv[3]=ca.w;
                cmv[4]=cb.x; cmv[5]=cb.y; cmv[6]=cb.z; cmv[7]=cb.w;
            }
            u16 ge[16];
            *(uint4*)&ge[0] = *(const uint4*)&gate[(size_t)row * 256 + base0];
            *(uint4*)&ge[8] = *(const uint4*)&gate[(size_t)row * 256 + base1];
            float outv[16];
            #pragma unroll
            for (int half = 0; half < 2; half++) {
                const int cb0 = half ? base1 : base0;
                #pragma unroll
                for (int t4 = 0; t4 < 2; t4++) {
                    float4 xa = *(const float4*)&X[(size_t)row * 256 + cb0 + t4 * 4];
                    float4 pa = *(const float4*)&pe[(size_t)pos * 256 + cb0 + t4 * 4];
                    #pragma unroll
                    for (int t = 0; t < 4; t++) {
                        const int idx = half * 8 + t4 * 4 + t;
                        const int col = cb0 + t4 * 4 + t;
                        float aw = bfc[col];
                        if (f1) {
                            #pragma unroll
                            for (int hh = 0; hh < 8; hh++) aw += 0.001f * wfc[hh * 256 + col];
                        } else {
                            #pragma unroll
                            for (int hh = 0; hh < 8; hh++) aw += cmv[hh] * wfc[hh * 256 + col];
                        }
                        float e = (&xa.x)[t] + sc * (&pa.x)[t];
                        outv[idx] = e + v[idx] * b2f(ge[idx]) * sigm(aw);
                    }
                }
            }
            float* Op = cfgs.out + (size_t)orow * 256;
            *(float4*)&Op[base0]     = *(float4*)&outv[0];
            *(float4*)&Op[base0 + 4] = *(float4*)&outv[4];
            *(float4*)&Op[base1]     = *(float4*)&outv[8];
            *(float4*)&Op[base1 + 4] = *(float4*)&outv[12];
        }
        if (hasNext) {
            asm volatile("s_waitcnt vmcnt(0)" ::: "memory");
            __syncthreads();
        }
    }
}

// ---------------- attention: one block per (b,h), no-max softmax, 2 sweeps ----------------
__global__ __launch_bounds__(512) void attn_kernel(
        const u16* __restrict__ Qd, const u16* __restrict__ Kd, const u16* __restrict__ Vd,
        const u16* __restrict__ Kp, const u16* __restrict__ Vp, const u16* __restrict__ Qp,
        const float* __restrict__ alpha,
        u16* __restrict__ ctx_d, u16* __restrict__ ctx_p, float* __restrict__ cm) {
    __shared__ u16 Ks[2][64 * 64];
    __shared__ union {
        struct { u16 VpT[2][32 * 64]; u16 Pm[320 * 64]; } s1;
        struct { u16 PT[64 * 320]; u16 VdT[32 * 320]; } s2;
    } U;
    __shared__ float r_l[320];
    __shared__ float colpart[8][64];

    const int bh = blockIdx.x, b = bh >> 3, h = bh & 7;
    const int tid = threadIdx.x;
    const int w = tid >> 6, lane = tid & 63, ln = lane & 15, g = lane >> 4;

    const float a = sigm(alpha[0]);
    const float inv = 0.1767766952966369f;
    const float sa = a * inv, sb = (1.0f - a) * inv;
    const int nmt = (w < 4) ? 3 : 2;
    const int mtsA[3] = { w, w + 8, w + 16 };

    const size_t rbd = (size_t)b * DLn * 256 + h * 32;
    const size_t rbp = (size_t)b * PLc * 256 + h * 32;

    bf16x8 Qf[3][2];
    #pragma unroll
    for (int t = 0; t < 3; t++) {
        const int i = mtsA[t] * 16 + ln;
        #pragma unroll
        for (int ks = 0; ks < 2; ks++) {
            u16 o[8] = {0,0,0,0,0,0,0,0};
            if (t < nmt && i < DLn) {
                const u16* src = (ks ? Kd : Qd) + rbd + (size_t)i * 256 + g * 8;
                const float s = ks ? sb : sa;
                uint4 v = *(const uint4*)src;
                u16 e[8]; *(uint4*)e = v;
                #pragma unroll
                for (int q = 0; q < 8; q++) o[q] = f2b(b2f(e[q]) * s);
            }
            Qf[t][ks] = *(bf16x8*)o;
        }
    }

    const int s_jj = tid >> 3, s_ch = tid & 7;
    const u16* s_src = ((s_ch >> 2) ? Qp : Kp) + rbp + (s_ch & 3) * 8;
    const int v_j = tid & 63, v_d0 = (tid >> 6) * 4;

    {
        int j = s_jj;
        uint4 kv = (j < PLc) ? *(const uint4*)(s_src + (size_t)j * 256) : make_uint4(0,0,0,0);
        uint2 vv = (v_j < PLc) ? *(const uint2*)(Vp + rbp + (size_t)v_j * 256 + v_d0) : make_uint2(0,0);
        *(uint4*)&Ks[0][sw(s_jj, s_ch * 8, 64)] = kv;
        u16 e[4]; *(uint2*)e = vv;
        #pragma unroll
        for (int q = 0; q < 4; q++) U.s1.VpT[0][sw(v_d0 + q, v_j, 64)] = e[q];
    }
    __syncthreads();

    float rs[3] = {0.f, 0.f, 0.f};
    f32x4 accd[3][2] = {};
    for (int jt = 0; jt < 16; jt++) {
        const int cur = jt & 1, j0 = jt * 64;
        const int jn = j0 + 64 + s_jj;
        uint4 kv = (jn < PLc) ? *(const uint4*)(s_src + (size_t)jn * 256) : make_uint4(0,0,0,0);
        const int vn = j0 + 64 + v_j;
        uint2 vv = (vn < PLc) ? *(const uint2*)(Vp + rbp + (size_t)vn * 256 + v_d0) : make_uint2(0,0);

        bf16x8 kf[4][2];
        #pragma unroll
        for (int js = 0; js < 4; js++)
            #pragma unroll
            for (int ks = 0; ks < 2; ks++)
                kf[js][ks] = *(const bf16x8*)&Ks[cur][sw(js * 16 + ln, ks * 32 + g * 8, 64)];

        #pragma unroll
        for (int t = 0; t < 3; t++) {
            if (t >= nmt) break;
            const int mt = mtsA[t];
            f32x4 acc[4] = {};
            #pragma unroll
            for (int ks = 0; ks < 2; ks++)
                #pragma unroll
                for (int js = 0; js < 4; js++)
                    acc[js] = __builtin_amdgcn_mfma_f32_16x16x32_bf16(kf[js][ks], Qf[t][ks], acc[js], 0, 0, 0);
            const int irow = mt * 16 + ln;
            #pragma unroll
            for (int js = 0; js < 4; js++) {
                u16 pb[4];
                float psum = 0.f;
                #pragma unroll
                for (int r = 0; r < 4; r++) {
                    float p = __expf(acc[js][r]);
                    psum += p;
                    pb[r] = f2b(p);
                }
                rs[t] += psum;
                *(ushort4*)&U.s1.Pm[sw(irow, js * 16 + g * 4, 64)] = *(ushort4*)pb;
            }
        }
        #pragma unroll
        for (int t = 0; t < 3; t++) {
            if (t >= nmt) break;
            const int mt = mtsA[t];
            #pragma unroll
            for (int ks2 = 0; ks2 < 2; ks2++) {
                bf16x8 af = *(const bf16x8*)&U.s1.Pm[sw(mt * 16 + ln, ks2 * 32 + g * 8, 64)];
                #pragma unroll
                for (int nd = 0; nd < 2; nd++) {
                    bf16x8 bv = *(const bf16x8*)&U.s1.VpT[cur][sw(nd * 16 + ln, ks2 * 32 + g * 8, 64)];
                    accd[t][nd] = __builtin_amdgcn_mfma_f32_16x16x32_bf16(bv, af, accd[t][nd], 0, 0, 0);
                }
            }
        }
        *(uint4*)&Ks[cur ^ 1][sw(s_jj, s_ch * 8, 64)] = kv;
        {
            u16 e[4]; *(uint2*)e = vv;
            #pragma unroll
            for (int q = 0; q < 4; q++) U.s1.VpT[cur ^ 1][sw(v_d0 + q, v_j, 64)] = e[q];
        }
        __syncthreads();
    }

    #pragma unroll
    for (int t = 0; t < 3; t++) {
        float v = rs[t];
        v += __shfl_xor(v, 16);
        v += __shfl_xor(v, 32);
        rs[t] = v;
    }
    if (g == 0) {
        #pragma unroll
        for (int t = 0; t < 3; t++) {
            if (t >= nmt) break;
            const int i = mtsA[t] * 16 + ln;
            r_l[i] = (i < DLn) ? 1.0f / (rs[t] - 24.0f) : 0.0f;
        }
    }
    __syncthreads();

    #pragma unroll
    for (int t = 0; t < 3; t++) {
        if (t >= nmt) break;
        const int i = mtsA[t] * 16 + ln;
        if (i < DLn) {
            const float ri = r_l[i];
            #pragma unroll
            for (int nd = 0; nd < 2; nd++) {
                u16 o[4];
                #pragma unroll
                for (int r = 0; r < 4; r++) o[r] = f2b(accd[t][nd][r] * ri);
                *(uint2*)&ctx_d[rbd + (size_t)i * 256 + nd * 16 + g * 4] = *(uint2*)o;
            }
        }
    }
    for (int c = tid; c < 320 * 8; c += 512) {
        const int i = c >> 3, d0 = (c & 7) * 4;
        u16 o[4] = {0,0,0,0};
        if (i < DLn) {
            const float ri = r_l[i];
            uint2 v = *(const uint2*)(Vd + rbd + (size_t)i * 256 + d0);
            u16 e[4]; *(uint2*)e = v;
            #pragma unroll
            for (int q = 0; q < 4; q++) o[q] = f2b(b2f(e[q]) * ri);
        }
        #pragma unroll
        for (int q = 0; q < 4; q++) U.s2.VdT[sw(d0 + q, i, 320)] = o[q];
    }
    {
        int j = s_jj;
        uint4 kv = (j < PLc) ? *(const uint4*)(s_src + (size_t)j * 256) : make_uint4(0,0,0,0);
        *(uint4*)&Ks[0][sw(s_jj, s_ch * 8, 64)] = kv;
    }
    float rr[3][4];
    #pragma unroll
    for (int t = 0; t < 3; t++)
        #pragma unroll
        for (int r = 0; r < 4; r++)
            rr[t][r] = (t < nmt) ? r_l[mtsA[t] * 16 + g * 4 + r] : 0.0f;
    __syncthreads();

    for (int jt = 0; jt < 16; jt++) {
        const int cur = jt & 1, j0 = jt * 64;
        const int jn = j0 + 64 + s_jj;
        uint4 kv = (jn < PLc) ? *(const uint4*)(s_src + (size_t)jn * 256) : make_uint4(0,0,0,0);

        bf16x8 kf[4][2];
        #pragma unroll
        for (int js = 0; js < 4; js++)
            #pragma unroll
            for (int ks = 0; ks < 2; ks++)
                kf[js][ks] = *(const bf16x8*)&Ks[cur][sw(js * 16 + ln, ks * 32 + g * 8, 64)];

        float csl[4] = {0.f, 0.f, 0.f, 0.f};
        #pragma unroll
        for (int t = 0; t < 3; t++) {
            if (t >= nmt) break;
            const int mt = mtsA[t];
            f32x4 acc[4] = {};
            #pragma unroll
            for (int ks = 0; ks < 2; ks++)
                #pragma unroll
                for (int js = 0; js < 4; js++)
                    acc[js] = __builtin_amdgcn_mfma_f32_16x16x32_bf16(Qf[t][ks], kf[js][ks], acc[js], 0, 0, 0);
            #pragma unroll
            for (int js = 0; js < 4; js++) {
                u16 pb[4];
                #pragma unroll
                for (int r = 0; r < 4; r++) {
                    float p = __expf(acc[js][r]);
                    csl[js] += p * rr[t][r];
                    pb[r] = f2b(p);
                }
                *(ushort4*)&U.s2.PT[sw(js * 16 + ln, mt * 16 + g * 4, 320)] = *(ushort4*)pb;
            }
        }
        #pragma unroll
        for (int js = 0; js < 4; js++) {
            float v = csl[js];
            v += __shfl_xor(v, 16);
            v += __shfl_xor(v, 32);
            csl[js] = v;
        }
        if (g == 0) {
            #pragma unroll
            for (int js = 0; js < 4; js++) colpart[w][js * 16 + ln] = csl[js];
        }
        *(uint4*)&Ks[cur ^ 1][sw(s_jj, s_ch * 8, 64)] = kv;
        __syncthreads();

        {
            const int js2 = w & 3, ds2 = w >> 2;
            f32x4 ap = {};
            #pragma unroll
            for (int k = 0; k < 10; k++) {
                bf16x8 af = *(const bf16x8*)&U.s2.PT[sw(js2 * 16 + ln, k * 32 + g * 8, 320)];
                bf16x8 bv = *(const bf16x8*)&U.s2.VdT[sw(ds2 * 16 + ln, k * 32 + g * 8, 320)];
                ap = __builtin_amdgcn_mfma_f32_16x16x32_bf16(bv, af, ap, 0, 0, 0);
            }
            const int j = j0 + js2 * 16 + ln;
            if (j < PLc) {
                u16 o[4];
                #pragma unroll
                for (int r = 0; r < 4; r++) o[r] = f2b(ap[r]);
                *(uint2*)&ctx_p[rbp + (size_t)j * 256 + ds2 * 16 + g * 4] = *(uint2*)o;
            }
        }
        if (w == 0) {
            float tot = 0.f;
            #pragma unroll
            for (int ww = 0; ww < 8; ww++) tot += colpart[ww][lane];
            const int j = j0 + lane;
            if (j < PLc) cm[(size_t)(b * PLc + j) * 8 + h] = tot * (1.0f / 290.0f);
        }
        __syncthreads();
    }
}

extern "C" void kernel_launch(void* const* d_in, const int* in_sizes, int n_in,
                              void* d_out, int out_size, void* d_ws, size_t ws_size,
                              hipStream_t stream) {
    (void)in_sizes; (void)n_in; (void)out_size;
    const float* drug    = (const float*)d_in[0];
    const float* prot    = (const float*)d_in[1];
    const float* scale_d = (const float*)d_in[2];
    const float* scale_p = (const float*)d_in[3];

    char* ws = (char*)d_ws;
    size_t off = 0;
    auto alloc = [&](size_t bytes) -> void* {
        void* p = ws + off;
        off += (bytes + 255) & ~(size_t)255;
        return p;
    };
    float* pe   = (float*)alloc((size_t)1000 * 256 * 4);
    u16* wt     = (u16*)alloc((size_t)10 * 65536 * 2);
    u16* Qd     = (u16*)alloc((size_t)MD * 256 * 2);
    u16* Kd     = (u16*)alloc((size_t)MD * 256 * 2);
    u16* Vd     = (u16*)alloc((size_t)MD * 256 * 2);
    u16* gate_d = (u16*)alloc((size_t)MD * 256 * 2);
    u16* Kp     = (u16*)alloc((size_t)MP * 256 * 2);
    u16* Vp     = (u16*)alloc((size_t)MP * 256 * 2);
    u16* Qp     = (u16*)alloc((size_t)MP * 256 * 2);
    u16* gate_p = (u16*)alloc((size_t)MP * 256 * 2);
    u16* ctxd   = (u16*)alloc((size_t)MD * 256 * 2);
    u16* ctxp   = (u16*)alloc((size_t)MP * 256 * 2);
    float* cm   = (float*)alloc((size_t)MP * 8 * 4);
    if (off > ws_size) return;

    pe_kernel<<<1000, 256, 0, stream>>>(pe);

    WPtrs wp;
    const int wsrc[10] = {4, 12, 14, 25, 6, 8, 10, 27, 16, 18};
    for (int m = 0; m < 10; m++) wp.w[m] = (const float*)d_in[wsrc[m]];
    wprep_kernel<<<dim3(16, 10), 256, 0, stream>>>(wp, wt);

    auto W = [&](int slot) { return wt + (size_t)slot * 65536; };
    const int GRID = ((NSTRIP + 7) / 8) * 8 * 4;   // 2592, XCD-colocated decode

    PCfg2 p1 = {};
    p1.c0 = { nullptr, drug, scale_d, pe, DLn,
              { { W(0), (const float*)d_in[5],  Qd,     0 },
                { W(1), (const float*)d_in[13], Kd,     0 },
                { W(2), (const float*)d_in[15], Vd,     0 },
                { W(3), (const float*)d_in[26], gate_d, 1 } } };
    p1.c1 = { nullptr, prot, scale_p, pe, PLc,
              { { W(4), (const float*)d_in[7],  Kp,     0 },
                { W(5), (const float*)d_in[9],  Vp,     0 },
                { W(6), (const float*)d_in[11], Qp,     0 },
                { W(7), (const float*)d_in[28], gate_p, 1 } } };
    proj_kernel<4><<<GRID, 256, 0, stream>>>(p1);

    attn_kernel<<<256, 512, 0, stream>>>(Qd, Kd, Vd, Kp, Vp, Qp,
                                         (const float*)d_in[20], ctxd, ctxp, cm);

    // proj2 + fused combine
    PCfg2 p2 = {};
    p2.c0 = { ctxd, nullptr, scale_d, pe, DLn,
              { { W(8), (const float*)d_in[17], nullptr, 0 }, {}, {}, {} } };
    p2.c1 = { ctxp, nullptr, scale_p, pe, PLc,
              { { W(9), (const float*)d_in[19], nullptr, 0 }, {}, {}, {} } };
    p2.x0 = drug;  p2.x1 = prot;
    p2.gate0 = gate_d;  p2.gate1 = gate_p;
    p2.cm = cm;
    p2.wfc0 = (const float*)d_in[21];  p2.bfc0 = (const float*)d_in[22];
    p2.wfc1 = (const float*)d_in[23];  p2.bfc1 = (const float*)d_in[24];
    p2.out = (float*)d_out;
    proj_kernel<1><<<GRID, 256, 0, stream>>>(p2);
}

// Round 11
// 185.050 us; speedup vs baseline: 1.7761x; 1.0559x over previous
//
#include <hip/hip_runtime.h>
#include <math.h>

typedef __attribute__((ext_vector_type(8))) short bf16x8;
typedef __attribute__((ext_vector_type(4))) float f32x4;
typedef unsigned short u16;
typedef unsigned int u32;

#define DEVFN static __device__ __forceinline__

constexpr int NB  = 32;
constexpr int DLn = 290;
constexpr int PLc = 1000;
constexpr int MD  = NB * DLn;   // 9280  = 145*64
constexpr int MP  = NB * PLc;   // 32000 = 500*64
constexpr int NSTRIP = 645;     // 145 + 500
constexpr int SPLIT  = 145;

DEVFN u16 f2b(float f) {
    u32 u = __builtin_bit_cast(u32, f);
    u32 r = u + 0x7fffu + ((u >> 16) & 1u);
    return (u16)(r >> 16);
}
DEVFN float b2f(u16 s) { return __builtin_bit_cast(float, (u32)s << 16); }
DEVFN float sigm(float x) { return 1.0f / (1.0f + __expf(-x)); }
// XOR-swizzled LDS index (u16 units); stride multiple of 8 u16. 16B-aligned.
DEVFN int sw(int row, int col, int stride) { return row * stride + (col ^ ((row & 7) << 3)); }

// ---------------- PE table ----------------
__global__ void pe_kernel(float* __restrict__ pe) {
    int p = blockIdx.x, c = threadIdx.x;
    float div = __expf((float)(c & ~1) * (-9.210340371976184f / 256.0f));
    float ang = (float)p * div;
    pe[p * 256 + c] = (c & 1) ? cosf(ang) : sinf(ang);
}

// ---------------- drug fc precompute: dfc[c] = b + 0.001*sum_h w[h][c] ----------------
__global__ void fcprep_kernel(const float* __restrict__ w, const float* __restrict__ b,
                              float* __restrict__ dfc) {
    int c = threadIdx.x;
    float s = b[c];
    #pragma unroll
    for (int hh = 0; hh < 8; hh++) s += 0.001f * w[hh * 256 + c];
    dfc[c] = s;
}

// ---------------- weight prep: WT[n][k] bf16, LDS transpose ----------------
struct WPtrs { const float* w[10]; };
__global__ __launch_bounds__(256) void wprep_kernel(WPtrs wp, u16* __restrict__ wt) {
    __shared__ u16 t[64][66];
    int m = blockIdx.y, tile = blockIdx.x;
    int k0 = (tile >> 2) * 64, n0 = (tile & 3) * 64;
    const float* w = wp.w[m];
    int r = threadIdx.x >> 6, c = threadIdx.x & 63;
    #pragma unroll
    for (int q = 0; q < 16; q++) {
        int rr = r + q * 4;
        t[rr][c] = f2b(w[(size_t)(k0 + rr) * 256 + n0 + c]);
    }
    __syncthreads();
    #pragma unroll
    for (int q = 0; q < 16; q++) {
        int rr = r + q * 4;
        wt[((size_t)m << 16) + (size_t)(n0 + rr) * 256 + k0 + c] = t[c][rr];
    }
}

// ---------------- fused projection ----------------
struct PM { const u16* BT; const float* bias; u16* C; int sig; };
struct PCfg {
    const u16* Ab;
    const float* Af32;
    const float* scale;
    const float* pe;
    int plen;
    PM m[4];
};
struct PCfg2 {
    PCfg c0, c1;
    // fused-combine extras (NM==1)
    const float* x0; const float* x1;
    const u16* gate0; const u16* gate1;
    const float* cm;
    const float* dfc;                       // precomputed drug attn logits [256]
    const float* wfc1; const float* bfc1;   // prot fc
    float* out;
};

// B staging via global_load_lds width 16. LDS dest pointer must be WAVE-UNIFORM
// (HW takes scalar base, adds lane*16B itself) -- per-lane dst forces a 64-iter
// waterfall. Swizzle + nu() folded into the per-lane GLOBAL source address.
DEVFN void stageB(const u16* __restrict__ BT, int c, u16* dst0, int tid) {
    const int wv = __builtin_amdgcn_readfirstlane(tid >> 6);   // wave id (SGPR)
    const int lane = tid & 63;
    #pragma unroll
    for (int k = 0; k < 8; k++) {
        const int r = k * 8 + wv * 2 + (lane >> 5);            // LDS row = B-slot
        const int nur = ((r >> 5) & 1) * 32 + ((r >> 2) & 3) * 8 + ((r >> 4) & 1) * 4 + (r & 3);
        const int kcol = (((lane & 31) ^ (r & 7)) << 3);       // inverse-swizzled col
        const u16* src = BT + (size_t)(c * 64 + nur) * 256 + kcol;
        u16* dst = dst0 + k * 2048 + wv * 512;                 // UNIFORM base
        __builtin_amdgcn_global_load_lds(
            (const __attribute__((address_space(1))) void*)src,
            (__attribute__((address_space(3))) void*)dst, 16, 0, 0);
    }
}

template<int NM>
__global__ __launch_bounds__(256, 4) void proj_kernel(PCfg2 cfgs) {
    const int d = blockIdx.x;
    const int x = d & 7, q = d >> 3;
    const int j = q & 3, sg = q >> 2;
    const int s = sg * 8 + x;
    if (s >= NSTRIP) return;
    const bool f1 = s < SPLIT;
    const int mt = f1 ? s : s - SPLIT;

    const u16*   Ab    = f1 ? cfgs.c0.Ab    : cfgs.c1.Ab;
    const float* Af32  = f1 ? cfgs.c0.Af32  : cfgs.c1.Af32;
    const float* scale = f1 ? cfgs.c0.scale : cfgs.c1.scale;
    const float* pe    = f1 ? cfgs.c0.pe    : cfgs.c1.pe;
    const int mi = (NM == 4) ? j : 0;
    const u16*   BT   = f1 ? (mi==0?cfgs.c0.m[0].BT  :mi==1?cfgs.c0.m[1].BT  :mi==2?cfgs.c0.m[2].BT  :cfgs.c0.m[3].BT)
                           : (mi==0?cfgs.c1.m[0].BT  :mi==1?cfgs.c1.m[1].BT  :mi==2?cfgs.c1.m[2].BT  :cfgs.c1.m[3].BT);
    const float* bias = f1 ? (mi==0?cfgs.c0.m[0].bias:mi==1?cfgs.c0.m[1].bias:mi==2?cfgs.c0.m[2].bias:cfgs.c0.m[3].bias)
                           : (mi==0?cfgs.c1.m[0].bias:mi==1?cfgs.c1.m[1].bias:mi==2?cfgs.c1.m[2].bias:cfgs.c1.m[3].bias);
    u16*         C    = f1 ? (mi==0?cfgs.c0.m[0].C   :mi==1?cfgs.c0.m[1].C   :mi==2?cfgs.c0.m[2].C   :cfgs.c0.m[3].C)
                           : (mi==0?cfgs.c1.m[0].C   :mi==1?cfgs.c1.m[1].C   :mi==2?cfgs.c1.m[2].C   :cfgs.c1.m[3].C);
    const int    sig  = f1 ? (mi==0?cfgs.c0.m[0].sig :mi==1?cfgs.c0.m[1].sig :mi==2?cfgs.c0.m[2].sig :cfgs.c0.m[3].sig)
                           : (mi==0?cfgs.c1.m[0].sig :mi==1?cfgs.c1.m[1].sig :mi==2?cfgs.c1.m[2].sig :cfgs.c1.m[3].sig);

    __shared__ u16 Bs[64 * 256];                         // 32 KB
    __shared__ float fcb[(NM == 1) ? 2304 : 4];          // prot fc weights (9 KB, NM==1)
    const int tid = threadIdx.x;
    const int lane = tid & 63, w = tid >> 6, ln = lane & 15, g = lane >> 4;

    // ---- first B stage issued BEFORE A-frag build (overlap) ----
    stageB(BT, (NM == 4) ? 0 : j, &Bs[0], tid);

    // ---- stage prot fc weights into LDS (NM==1, protein blocks) ----
    if (NM == 1 && !f1) {
        *(float4*)&fcb[tid * 8]     = *(const float4*)&cfgs.wfc1[tid * 8];
        *(float4*)&fcb[tid * 8 + 4] = *(const float4*)&cfgs.wfc1[tid * 8 + 4];
        fcb[2048 + tid] = cfgs.bfc1[tid];
    }

    // ---- A fragments in registers: row mt*64 + w*16 + ln, k = ks*32 + g*8 ----
    const int row = mt * 64 + w * 16 + ln;
    bf16x8 Af[8];
    {
        if (Af32) {
            const int i = f1 ? (row % DLn) : (row % PLc);
            const float sc = scale[0];
            const float* Xp_ = Af32 + (size_t)row * 256 + g * 8;
            const float* Pe_ = pe + (size_t)i * 256 + g * 8;
            #pragma unroll
            for (int ks = 0; ks < 8; ks++) {
                float4 xa = *(const float4*)(Xp_ + ks * 32);
                float4 xb = *(const float4*)(Xp_ + ks * 32 + 4);
                float4 pa = *(const float4*)(Pe_ + ks * 32);
                float4 pb = *(const float4*)(Pe_ + ks * 32 + 4);
                u16 o[8];
                o[0] = f2b(xa.x + sc * pa.x); o[1] = f2b(xa.y + sc * pa.y);
                o[2] = f2b(xa.z + sc * pa.z); o[3] = f2b(xa.w + sc * pa.w);
                o[4] = f2b(xb.x + sc * pb.x); o[5] = f2b(xb.y + sc * pb.y);
                o[6] = f2b(xb.z + sc * pb.z); o[7] = f2b(xb.w + sc * pb.w);
                Af[ks] = *(bf16x8*)o;
            }
        } else {
            const u16* Ap = Ab + (size_t)row * 256 + g * 8;
            #pragma unroll
            for (int ks = 0; ks < 8; ks++)
                Af[ks] = *(const bf16x8*)(Ap + ks * 32);
        }
    }
    asm volatile("s_waitcnt vmcnt(0)" ::: "memory");
    __syncthreads();

    #pragma unroll
    for (int c = 0; c < ((NM == 4) ? 4 : 1); c++) {
        const int chunk = (NM == 4) ? c : j;
        // compute: D = Bfrag * Afrag  (C^T fragment)
        f32x4 acc[4] = {};
        #pragma unroll
        for (int ks = 0; ks < 8; ks++) {
            #pragma unroll
            for (int nt = 0; nt < 4; nt++) {
                bf16x8 bf = *(const bf16x8*)&Bs[sw(nt * 16 + ln, ks * 32 + g * 8, 256)];
                acc[nt] = __builtin_amdgcn_mfma_f32_16x16x32_bf16(bf, Af[ks], acc[nt], 0, 0, 0);
            }
        }
        const bool hasNext = (NM == 4) && (c < 3);
        if (hasNext) {
            __syncthreads();                 // all waves done reading Bs
            stageB(BT, c + 1, &Bs[0], tid);  // overwrite; epilogue overlaps flight
        }
        const int base0 = chunk * 64 + g * 8, base1 = base0 + 32;
        f32x4 b0 = *(const f32x4*)&bias[base0];
        f32x4 b1 = *(const f32x4*)&bias[base0 + 4];
        f32x4 b2 = *(const f32x4*)&bias[base1];
        f32x4 b3 = *(const f32x4*)&bias[base1 + 4];
        float v[16];
        #pragma unroll
        for (int t = 0; t < 4; t++) {
            v[t]      = acc[0][t] + b0[t];
            v[4 + t]  = acc[1][t] + b1[t];
            v[8 + t]  = acc[2][t] + b2[t];
            v[12 + t] = acc[3][t] + b3[t];
        }
        if (NM == 4) {
            if (sig) {
                #pragma unroll
                for (int t = 0; t < 16; t++) v[t] = sigm(v[t]);
            }
            u16 o[16];
            #pragma unroll
            for (int t = 0; t < 16; t++) o[t] = f2b(v[t]);
            u16* Cp = C + (size_t)row * 256;
            *(uint4*)&Cp[base0] = *(uint4*)&o[0];
            *(uint4*)&Cp[base1] = *(uint4*)&o[8];
        } else {
            // fused combine: out = e + v*gate*sigm(aw), fp32
            (void)C; (void)sig;
            const float* X   = f1 ? cfgs.x0 : cfgs.x1;
            const u16* gate  = f1 ? cfgs.gate0 : cfgs.gate1;
            const float sc   = scale[0];
            const int pos  = f1 ? (row % DLn) : (row % PLc);
            const int bidx = f1 ? (row / DLn) : (row / PLc);
            const int orow = bidx * 1290 + (f1 ? pos : 290 + pos);
            float aw[16];
            if (f1) {
                const float* dfc = cfgs.dfc;
                *(float4*)&aw[0]  = *(const float4*)&dfc[base0];
                *(float4*)&aw[4]  = *(const float4*)&dfc[base0 + 4];
                *(float4*)&aw[8]  = *(const float4*)&dfc[base1];
                *(float4*)&aw[12] = *(const float4*)&dfc[base1 + 4];
            } else {
                float cmv[8];
                float4 ca = *(const float4*)&cfgs.cm[(size_t)row * 8];
                float4 cb = *(const float4*)&cfgs.cm[(size_t)row * 8 + 4];
                cmv[0]=ca.x; cmv[1]=ca.y; cmv[2]=ca.z; cmv[3]=ca.w;
                cmv[4]=cb.x; cmv[5]=cb.y; cmv[6]=cb.z; cmv[7]=cb.w;
                #pragma unroll
                for (int t = 0; t < 16; t++) {
                    const int col = (t < 8) ? (base0 + t) : (base1 + t - 8);
                    float s2 = fcb[2048 + col];
                    #pragma unroll
                    for (int hh = 0; hh < 8; hh++) s2 += cmv[hh] * fcb[hh * 256 + col];
                    aw[t] = s2;
                }
            }
            u16 ge[16];
            *(uint4*)&ge[0] = *(const uint4*)&gate[(size_t)row * 256 + base0];
            *(uint4*)&ge[8] = *(const uint4*)&gate[(size_t)row * 256 + base1];
            float outv[16];
            #pragma unroll
            for (int half = 0; half < 2; half++) {
                const int cb0 = half ? base1 : base0;
                #pragma unroll
                for (int t4 = 0; t4 < 2; t4++) {
                    float4 xa = *(const float4*)&X[(size_t)row * 256 + cb0 + t4 * 4];
                    float4 pa = *(const float4*)&pe[(size_t)pos * 256 + cb0 + t4 * 4];
                    #pragma unroll
                    for (int t = 0; t < 4; t++) {
                        const int idx = half * 8 + t4 * 4 + t;
                        float e = (&xa.x)[t] + sc * (&pa.x)[t];
                        outv[idx] = e + v[idx] * b2f(ge[idx]) * sigm(aw[idx]);
                    }
                }
            }
            float* Op = cfgs.out + (size_t)orow * 256;
            *(float4*)&Op[base0]     = *(float4*)&outv[0];
            *(float4*)&Op[base0 + 4] = *(float4*)&outv[4];
            *(float4*)&Op[base1]     = *(float4*)&outv[8];
            *(float4*)&Op[base1 + 4] = *(float4*)&outv[12];
        }
        if (hasNext) {
            asm volatile("s_waitcnt vmcnt(0)" ::: "memory");
            __syncthreads();
        }
    }
}

// ---------------- attention: one block per (b,h), no-max softmax, 2 sweeps ----------------
__global__ __launch_bounds__(512) void attn_kernel(
        const u16* __restrict__ Qd, const u16* __restrict__ Kd, const u16* __restrict__ Vd,
        const u16* __restrict__ Kp, const u16* __restrict__ Vp, const u16* __restrict__ Qp,
        const float* __restrict__ alpha,
        u16* __restrict__ ctx_d, u16* __restrict__ ctx_p, float* __restrict__ cm) {
    __shared__ u16 Ks[2][64 * 64];
    __shared__ union {
        struct { u16 VpT[2][32 * 64]; u16 Pm[320 * 64]; } s1;
        struct { u16 PT[64 * 320]; u16 VdT[32 * 320]; } s2;
    } U;
    __shared__ float r_l[320];
    __shared__ float colpart[8][64];

    const int bh = blockIdx.x, b = bh >> 3, h = bh & 7;
    const int tid = threadIdx.x;
    const int w = tid >> 6, lane = tid & 63, ln = lane & 15, g = lane >> 4;

    const float a = sigm(alpha[0]);
    const float inv = 0.1767766952966369f;
    const float sa = a * inv, sb = (1.0f - a) * inv;
    const int nmt = (w < 4) ? 3 : 2;
    const int mtsA[3] = { w, w + 8, w + 16 };

    const size_t rbd = (size_t)b * DLn * 256 + h * 32;
    const size_t rbp = (size_t)b * PLc * 256 + h * 32;

    bf16x8 Qf[3][2];
    #pragma unroll
    for (int t = 0; t < 3; t++) {
        const int i = mtsA[t] * 16 + ln;
        #pragma unroll
        for (int ks = 0; ks < 2; ks++) {
            u16 o[8] = {0,0,0,0,0,0,0,0};
            if (t < nmt && i < DLn) {
                const u16* src = (ks ? Kd : Qd) + rbd + (size_t)i * 256 + g * 8;
                const float s = ks ? sb : sa;
                uint4 v = *(const uint4*)src;
                u16 e[8]; *(uint4*)e = v;
                #pragma unroll
                for (int q = 0; q < 8; q++) o[q] = f2b(b2f(e[q]) * s);
            }
            Qf[t][ks] = *(bf16x8*)o;
        }
    }

    const int s_jj = tid >> 3, s_ch = tid & 7;
    const u16* s_src = ((s_ch >> 2) ? Qp : Kp) + rbp + (s_ch & 3) * 8;
    const int v_j = tid & 63, v_d0 = (tid >> 6) * 4;

    {
        int j = s_jj;
        uint4 kv = (j < PLc) ? *(const uint4*)(s_src + (size_t)j * 256) : make_uint4(0,0,0,0);
        uint2 vv = (v_j < PLc) ? *(const uint2*)(Vp + rbp + (size_t)v_j * 256 + v_d0) : make_uint2(0,0);
        *(uint4*)&Ks[0][sw(s_jj, s_ch * 8, 64)] = kv;
        u16 e[4]; *(uint2*)e = vv;
        #pragma unroll
        for (int q = 0; q < 4; q++) U.s1.VpT[0][sw(v_d0 + q, v_j, 64)] = e[q];
    }
    __syncthreads();

    float rs[3] = {0.f, 0.f, 0.f};
    f32x4 accd[3][2] = {};
    for (int jt = 0; jt < 16; jt++) {
        const int cur = jt & 1, j0 = jt * 64;
        const int jn = j0 + 64 + s_jj;
        uint4 kv = (jn < PLc) ? *(const uint4*)(s_src + (size_t)jn * 256) : make_uint4(0,0,0,0);
        const int vn = j0 + 64 + v_j;
        uint2 vv = (vn < PLc) ? *(const uint2*)(Vp + rbp + (size_t)vn * 256 + v_d0) : make_uint2(0,0);

        bf16x8 kf[4][2];
        #pragma unroll
        for (int js = 0; js < 4; js++)
            #pragma unroll
            for (int ks = 0; ks < 2; ks++)
                kf[js][ks] = *(const bf16x8*)&Ks[cur][sw(js * 16 + ln, ks * 32 + g * 8, 64)];

        #pragma unroll
        for (int t = 0; t < 3; t++) {
            if (t >= nmt) break;
            const int mt = mtsA[t];
            f32x4 acc[4] = {};
            #pragma unroll
            for (int ks = 0; ks < 2; ks++)
                #pragma unroll
                for (int js = 0; js < 4; js++)
                    acc[js] = __builtin_amdgcn_mfma_f32_16x16x32_bf16(kf[js][ks], Qf[t][ks], acc[js], 0, 0, 0);
            const int irow = mt * 16 + ln;
            #pragma unroll
            for (int js = 0; js < 4; js++) {
                u16 pb[4];
                float psum = 0.f;
                #pragma unroll
                for (int r = 0; r < 4; r++) {
                    float p = __expf(acc[js][r]);
                    psum += p;
                    pb[r] = f2b(p);
                }
                rs[t] += psum;
                *(ushort4*)&U.s1.Pm[sw(irow, js * 16 + g * 4, 64)] = *(ushort4*)pb;
            }
        }
        #pragma unroll
        for (int t = 0; t < 3; t++) {
            if (t >= nmt) break;
            const int mt = mtsA[t];
            #pragma unroll
            for (int ks2 = 0; ks2 < 2; ks2++) {
                bf16x8 af = *(const bf16x8*)&U.s1.Pm[sw(mt * 16 + ln, ks2 * 32 + g * 8, 64)];
                #pragma unroll
                for (int nd = 0; nd < 2; nd++) {
                    bf16x8 bv = *(const bf16x8*)&U.s1.VpT[cur][sw(nd * 16 + ln, ks2 * 32 + g * 8, 64)];
                    accd[t][nd] = __builtin_amdgcn_mfma_f32_16x16x32_bf16(bv, af, accd[t][nd], 0, 0, 0);
                }
            }
        }
        *(uint4*)&Ks[cur ^ 1][sw(s_jj, s_ch * 8, 64)] = kv;
        {
            u16 e[4]; *(uint2*)e = vv;
            #pragma unroll
            for (int q = 0; q < 4; q++) U.s1.VpT[cur ^ 1][sw(v_d0 + q, v_j, 64)] = e[q];
        }
        __syncthreads();
    }

    #pragma unroll
    for (int t = 0; t < 3; t++) {
        float v = rs[t];
        v += __shfl_xor(v, 16);
        v += __shfl_xor(v, 32);
        rs[t] = v;
    }
    if (g == 0) {
        #pragma unroll
        for (int t = 0; t < 3; t++) {
            if (t >= nmt) break;
            const int i = mtsA[t] * 16 + ln;
            r_l[i] = (i < DLn) ? 1.0f / (rs[t] - 24.0f) : 0.0f;
        }
    }
    __syncthreads();

    #pragma unroll
    for (int t = 0; t < 3; t++) {
        if (t >= nmt) break;
        const int i = mtsA[t] * 16 + ln;
        if (i < DLn) {
            const float ri = r_l[i];
            #pragma unroll
            for (int nd = 0; nd < 2; nd++) {
                u16 o[4];
                #pragma unroll
                for (int r = 0; r < 4; r++) o[r] = f2b(accd[t][nd][r] * ri);
                *(uint2*)&ctx_d[rbd + (size_t)i * 256 + nd * 16 + g * 4] = *(uint2*)o;
            }
        }
    }
    for (int c = tid; c < 320 * 8; c += 512) {
        const int i = c >> 3, d0 = (c & 7) * 4;
        u16 o[4] = {0,0,0,0};
        if (i < DLn) {
            const float ri = r_l[i];
            uint2 v = *(const uint2*)(Vd + rbd + (size_t)i * 256 + d0);
            u16 e[4]; *(uint2*)e = v;
            #pragma unroll
            for (int q = 0; q < 4; q++) o[q] = f2b(b2f(e[q]) * ri);
        }
        #pragma unroll
        for (int q = 0; q < 4; q++) U.s2.VdT[sw(d0 + q, i, 320)] = o[q];
    }
    {
        int j = s_jj;
        uint4 kv = (j < PLc) ? *(const uint4*)(s_src + (size_t)j * 256) : make_uint4(0,0,0,0);
        *(uint4*)&Ks[0][sw(s_jj, s_ch * 8, 64)] = kv;
    }
    float rr[3][4];
    #pragma unroll
    for (int t = 0; t < 3; t++)
        #pragma unroll
        for (int r = 0; r < 4; r++)
            rr[t][r] = (t < nmt) ? r_l[mtsA[t] * 16 + g * 4 + r] : 0.0f;
    __syncthreads();

    for (int jt = 0; jt < 16; jt++) {
        const int cur = jt & 1, j0 = jt * 64;
        const int jn = j0 + 64 + s_jj;
        uint4 kv = (jn < PLc) ? *(const uint4*)(s_src + (size_t)jn * 256) : make_uint4(0,0,0,0);

        bf16x8 kf[4][2];
        #pragma unroll
        for (int js = 0; js < 4; js++)
            #pragma unroll
            for (int ks = 0; ks < 2; ks++)
                kf[js][ks] = *(const bf16x8*)&Ks[cur][sw(js * 16 + ln, ks * 32 + g * 8, 64)];

        float csl[4] = {0.f, 0.f, 0.f, 0.f};
        #pragma unroll
        for (int t = 0; t < 3; t++) {
            if (t >= nmt) break;
            const int mt = mtsA[t];
            f32x4 acc[4] = {};
            #pragma unroll
            for (int ks = 0; ks < 2; ks++)
                #pragma unroll
                for (int js = 0; js < 4; js++)
                    acc[js] = __builtin_amdgcn_mfma_f32_16x16x32_bf16(Qf[t][ks], kf[js][ks], acc[js], 0, 0, 0);
            #pragma unroll
            for (int js = 0; js < 4; js++) {
                u16 pb[4];
                #pragma unroll
                for (int r = 0; r < 4; r++) {
                    float p = __expf(acc[js][r]);
                    csl[js] += p * rr[t][r];
                    pb[r] = f2b(p);
                }
                *(ushort4*)&U.s2.PT[sw(js * 16 + ln, mt * 16 + g * 4, 320)] = *(ushort4*)pb;
            }
        }
        #pragma unroll
        for (int js = 0; js < 4; js++) {
            float v = csl[js];
            v += __shfl_xor(v, 16);
            v += __shfl_xor(v, 32);
            csl[js] = v;
        }
        if (g == 0) {
            #pragma unroll
            for (int js = 0; js < 4; js++) colpart[w][js * 16 + ln] = csl[js];
        }
        *(uint4*)&Ks[cur ^ 1][sw(s_jj, s_ch * 8, 64)] = kv;
        __syncthreads();

        {
            const int js2 = w & 3, ds2 = w >> 2;
            f32x4 ap = {};
            #pragma unroll
            for (int k = 0; k < 10; k++) {
                bf16x8 af = *(const bf16x8*)&U.s2.PT[sw(js2 * 16 + ln, k * 32 + g * 8, 320)];
                bf16x8 bv = *(const bf16x8*)&U.s2.VdT[sw(ds2 * 16 + ln, k * 32 + g * 8, 320)];
                ap = __builtin_amdgcn_mfma_f32_16x16x32_bf16(bv, af, ap, 0, 0, 0);
            }
            const int j = j0 + js2 * 16 + ln;
            if (j < PLc) {
                u16 o[4];
                #pragma unroll
                for (int r = 0; r < 4; r++) o[r] = f2b(ap[r]);
                *(uint2*)&ctx_p[rbp + (size_t)j * 256 + ds2 * 16 + g * 4] = *(uint2*)o;
            }
        }
        if (w == 0) {
            float tot = 0.f;
            #pragma unroll
            for (int ww = 0; ww < 8; ww++) tot += colpart[ww][lane];
            const int j = j0 + lane;
            if (j < PLc) cm[(size_t)(b * PLc + j) * 8 + h] = tot * (1.0f / 290.0f);
        }
        __syncthreads();
    }
}

extern "C" void kernel_launch(void* const* d_in, const int* in_sizes, int n_in,
                              void* d_out, int out_size, void* d_ws, size_t ws_size,
                              hipStream_t stream) {
    (void)in_sizes; (void)n_in; (void)out_size;
    const float* drug    = (const float*)d_in[0];
    const float* prot    = (const float*)d_in[1];
    const float* scale_d = (const float*)d_in[2];
    const float* scale_p = (const float*)d_in[3];

    char* ws = (char*)d_ws;
    size_t off = 0;
    auto alloc = [&](size_t bytes) -> void* {
        void* p = ws + off;
        off += (bytes + 255) & ~(size_t)255;
        return p;
    };
    float* pe   = (float*)alloc((size_t)1000 * 256 * 4);
    u16* wt     = (u16*)alloc((size_t)10 * 65536 * 2);
    u16* Qd     = (u16*)alloc((size_t)MD * 256 * 2);
    u16* Kd     = (u16*)alloc((size_t)MD * 256 * 2);
    u16* Vd     = (u16*)alloc((size_t)MD * 256 * 2);
    u16* gate_d = (u16*)alloc((size_t)MD * 256 * 2);
    u16* Kp     = (u16*)alloc((size_t)MP * 256 * 2);
    u16* Vp     = (u16*)alloc((size_t)MP * 256 * 2);
    u16* Qp     = (u16*)alloc((size_t)MP * 256 * 2);
    u16* gate_p = (u16*)alloc((size_t)MP * 256 * 2);
    u16* ctxd   = (u16*)alloc((size_t)MD * 256 * 2);
    u16* ctxp   = (u16*)alloc((size_t)MP * 256 * 2);
    float* cm   = (float*)alloc((size_t)MP * 8 * 4);
    float* dfc  = (float*)alloc((size_t)256 * 4);
    if (off > ws_size) return;

    pe_kernel<<<1000, 256, 0, stream>>>(pe);
    fcprep_kernel<<<1, 256, 0, stream>>>((const float*)d_in[21], (const float*)d_in[22], dfc);

    WPtrs wp;
    const int wsrc[10] = {4, 12, 14, 25, 6, 8, 10, 27, 16, 18};
    for (int m = 0; m < 10; m++) wp.w[m] = (const float*)d_in[wsrc[m]];
    wprep_kernel<<<dim3(16, 10), 256, 0, stream>>>(wp, wt);

    auto W = [&](int slot) { return wt + (size_t)slot * 65536; };
    const int GRID = ((NSTRIP + 7) / 8) * 8 * 4;   // 2592, XCD-colocated decode

    PCfg2 p1 = {};
    p1.c0 = { nullptr, drug, scale_d, pe, DLn,
              { { W(0), (const float*)d_in[5],  Qd,     0 },
                { W(1), (const float*)d_in[13], Kd,     0 },
                { W(2), (const float*)d_in[15], Vd,     0 },
                { W(3), (const float*)d_in[26], gate_d, 1 } } };
    p1.c1 = { nullptr, prot, scale_p, pe, PLc,
              { { W(4), (const float*)d_in[7],  Kp,     0 },
                { W(5), (const float*)d_in[9],  Vp,     0 },
                { W(6), (const float*)d_in[11], Qp,     0 },
                { W(7), (const float*)d_in[28], gate_p, 1 } } };
    proj_kernel<4><<<GRID, 256, 0, stream>>>(p1);

    attn_kernel<<<256, 512, 0, stream>>>(Qd, Kd, Vd, Kp, Vp, Qp,
                                         (const float*)d_in[20], ctxd, ctxp, cm);

    PCfg2 p2 = {};
    p2.c0 = { ctxd, nullptr, scale_d, pe, DLn,
              { { W(8), (const float*)d_in[17], nullptr, 0 }, {}, {}, {} } };
    p2.c1 = { ctxp, nullptr, scale_p, pe, PLc,
              { { W(9), (const float*)d_in[19], nullptr, 0 }, {}, {}, {} } };
    p2.x0 = drug;  p2.x1 = prot;
    p2.gate0 = gate_d;  p2.gate1 = gate_p;
    p2.cm = cm;
    p2.dfc = dfc;
    p2.wfc1 = (const float*)d_in[23];  p2.bfc1 = (const float*)d_in[24];
    p2.out = (float*)d_out;
    proj_kernel<1><<<GRID, 256, 0, stream>>>(p2);
}